// Round 5
// baseline (575.808 us; speedup 1.0000x reference)
//
#include <hip/hip_runtime.h>

#define B_ 4
#define T_ 2048
#define S_ 2048
#define D_ 256
#define F_ 1024

typedef unsigned short ushort_t;
typedef __bf16 v8bf __attribute__((ext_vector_type(8)));
typedef float v4f __attribute__((ext_vector_type(4)));
typedef __attribute__((address_space(1))) const unsigned int gas_uint;
typedef __attribute__((address_space(3))) unsigned int las_uint;

__device__ __forceinline__ ushort_t f2bf(float f) {
  unsigned u = __float_as_uint(f);
  unsigned r = (u + 0x7FFFu + ((u >> 16) & 1u)) >> 16;   // RTNE
  return (ushort_t)r;
}

// ---------------------------------------------------------------------------
// Weight prep: fp32 [K,N] -> bf16 [N,K] (transpose + convert), 8 matrices.
// ---------------------------------------------------------------------------
struct WP { const float* s; ushort_t* d; int K, N; };
struct WP8 { WP m[8]; };

__global__ void prep_weights_k(WP8 a) {
  WP w = a.m[blockIdx.z];
  int k0 = blockIdx.x * 64, n0 = blockIdx.y * 64;
  if (k0 >= w.K || n0 >= w.N) return;
  __shared__ ushort_t tile[64][65];
  int tx = threadIdx.x, ty = threadIdx.y;
  for (int r = ty; r < 64; r += 4)
    tile[r][tx] = f2bf(w.s[(size_t)(k0 + r) * w.N + n0 + tx]);
  __syncthreads();
  for (int r = ty; r < 64; r += 4)
    w.d[(size_t)(n0 + r) * w.K + k0 + tx] = tile[tx][r];
}

// pack biases: bqkv1 = [bq1|bk1|bv1] (768), bkv2 = [bk2|bv2] (512)
__global__ void pack_bias_k(const float* bq1, const float* bk1, const float* bv1,
                            const float* bk2, const float* bv2,
                            float* bqkv1, float* bkv2) {
  int t = blockIdx.x * 256 + threadIdx.x;
  if (t < 768) bqkv1[t] = (t < 256) ? bq1[t] : (t < 512) ? bk1[t - 256] : bv1[t - 512];
  if (t < 512) bkv2[t] = (t < 256) ? bk2[t] : bv2[t - 256];
}

// fp32 -> bf16 elementwise for y and Z (grid.y selects tensor)
__global__ void cvt_k(const float* __restrict__ a, ushort_t* __restrict__ oa,
                      const float* __restrict__ b, ushort_t* __restrict__ ob) {
  int i = blockIdx.x * 256 + threadIdx.x;
  const float* s = blockIdx.y ? b : a;
  ushort_t* d = blockIdx.y ? ob : oa;
  size_t off = (size_t)i * 8;
  float4 v0 = *(const float4*)(s + off);
  float4 v1 = *(const float4*)(s + off + 4);
  union { ushort_t u[8]; uint4 v; } pk;
  pk.u[0] = f2bf(v0.x); pk.u[1] = f2bf(v0.y); pk.u[2] = f2bf(v0.z); pk.u[3] = f2bf(v0.w);
  pk.u[4] = f2bf(v1.x); pk.u[5] = f2bf(v1.y); pk.u[6] = f2bf(v1.z); pk.u[7] = f2bf(v1.w);
  *(uint4*)(d + off) = pk.v;
}

// bf16 [rows,cols] (row stride ldin, batch stride sIz) -> bf16 [cols,rows]
__global__ void transpose_bf16_k(const ushort_t* __restrict__ in, long long sIz, int ldin,
                                 ushort_t* __restrict__ out, long long sOz,
                                 int rows, int cols) {
  in  += (size_t)blockIdx.z * sIz;
  out += (size_t)blockIdx.z * sOz;
  __shared__ ushort_t tile[64][65];
  int r0 = blockIdx.x * 64, c0 = blockIdx.y * 64;
  int tx = threadIdx.x, ty = threadIdx.y;
  for (int r = ty; r < 64; r += 4)
    tile[r][tx] = in[(size_t)(r0 + r) * ldin + c0 + tx];
  __syncthreads();
  for (int r = ty; r < 64; r += 4)
    out[(size_t)(c0 + r) * rows + r0 + tx] = tile[tx][r];
}

// ---------------------------------------------------------------------------
// GEMM: C[M,N] = A[M,K] @ Bt[N,K]^T + bias (projections + FFN).  Verified.
// ---------------------------------------------------------------------------
template<bool RELU>
__global__ __launch_bounds__(256, 2) void gemm_bt(
    const ushort_t* __restrict__ A, int lda,
    const ushort_t* __restrict__ Bt, int ldb,
    const float* __restrict__ bias,
    float* __restrict__ Cf, ushort_t* __restrict__ Cb, int ldc, int K) {
  const int n0 = blockIdx.x * 64, m0 = blockIdx.y * 128;
  const int t = threadIdx.x, lane = t & 63, wv = t >> 6;
  const int wm = wv >> 1, wn = wv & 1;
  const int kslot = lane >> 4, l15 = lane & 15;
  __shared__ __align__(16) char smem[24576];   // A 16KB + B 8KB
  char* sA = smem;
  char* sB = smem + 16384;

  v4f acc[4][2];
  v4f zero = {0.f, 0.f, 0.f, 0.f};
#pragma unroll
  for (int m = 0; m < 4; ++m)
#pragma unroll
    for (int n = 0; n < 2; ++n) acc[m][n] = zero;

  for (int kk = 0; kk < K; kk += 64) {
    __syncthreads();
#pragma unroll
    for (int q = 0; q < 4; ++q) {
      int g = q * 256 + t;
      int row = g >> 3, j = g & 7;
      const ushort_t* src = A + (long long)(m0 + row) * lda + kk + ((j ^ (row & 7)) << 3);
      __builtin_amdgcn_global_load_lds((gas_uint*)src,
          (las_uint*)(sA + q * 4096 + (wv << 10)), 16, 0, 0);
    }
#pragma unroll
    for (int q = 0; q < 2; ++q) {
      int g = q * 256 + t;
      int row = g >> 3, j = g & 7;
      const ushort_t* src = Bt + (long long)(n0 + row) * ldb + kk + ((j ^ (row & 7)) << 3);
      __builtin_amdgcn_global_load_lds((gas_uint*)src,
          (las_uint*)(sB + q * 4096 + (wv << 10)), 16, 0, 0);
    }
    __syncthreads();
#pragma unroll
    for (int ks = 0; ks < 2; ++ks) {
      v8bf af[4]; v8bf bfr[2];
#pragma unroll
      for (int m = 0; m < 4; ++m) {
        int row = wm * 64 + m * 16 + l15;
        int gs = (ks * 4 + kslot) ^ (row & 7);
        af[m] = *(const v8bf*)(sA + ((row * 8 + gs) << 4));
      }
#pragma unroll
      for (int n = 0; n < 2; ++n) {
        int row = wn * 32 + n * 16 + l15;
        int gs = (ks * 4 + kslot) ^ (row & 7);
        bfr[n] = *(const v8bf*)(sB + ((row * 8 + gs) << 4));
      }
#pragma unroll
      for (int m = 0; m < 4; ++m)
#pragma unroll
        for (int n = 0; n < 2; ++n)
          acc[m][n] = __builtin_amdgcn_mfma_f32_16x16x32_bf16(af[m], bfr[n], acc[m][n], 0, 0, 0);
    }
  }
#pragma unroll
  for (int m = 0; m < 4; ++m) {
    int grow0 = m0 + wm * 64 + m * 16 + (kslot << 2);
#pragma unroll
    for (int n = 0; n < 2; ++n) {
      int gcol = n0 + wn * 32 + n * 16 + l15;
      float bb = bias ? bias[gcol] : 0.f;
#pragma unroll
      for (int i = 0; i < 4; ++i) {
        float v = acc[m][n][i] + bb;
        if (RELU) v = fmaxf(v, 0.f);
        long long off = (long long)(grow0 + i) * ldc + gcol;
        if (Cf) Cf[off] = v;
        if (Cb) Cb[off] = f2bf(v);
      }
    }
  }
}

// ---------------------------------------------------------------------------
// Flash attention, LDS-free / barrier-free.  One wave per block, 16 q-rows.
// Swapped QK^T: mfma(K, Q) -> D col = q = l15 (lane-local softmax row).
// P redistribution to PV B-fragments done fully in-register via 8 __shfl.
// All fragment mappings pinned by the verified gemm_bt (A-row=l15, B-row=l15,
// D row=kslot*4+i, col=l15; within-k granule convention cancels in the dot).
// ---------------------------------------------------------------------------
template<int CAUSAL>
__global__ __launch_bounds__(64) void flash_k(
    const ushort_t* __restrict__ QKV, const ushort_t* __restrict__ Vt,
    float* __restrict__ O) {
  const int b = blockIdx.y, q0 = blockIdx.x * 16;
  const int lane = threadIdx.x & 63;
  const int kslot = lane >> 4, l15 = lane & 15;
  const ushort_t* Qp = QKV + (size_t)b * T_ * 768;
  const ushort_t* Kp = Qp + 256;
  const ushort_t* Vb = Vt + (size_t)b * (size_t)D_ * S_;
  const int q = q0 + l15;

  // Q as B-fragment: row q (via l15), k = ks*32 + kslot*8 + j
  v8bf qf[8];
  {
    const ushort_t* qrow = Qp + (size_t)q * 768 + kslot * 8;
#pragma unroll
    for (int ks = 0; ks < 8; ++ks) qf[ks] = *(const v8bf*)(qrow + ks * 32);
  }
  v4f acc_o[16];
  v4f zero = {0.f, 0.f, 0.f, 0.f};
#pragma unroll
  for (int td = 0; td < 16; ++td) acc_o[td] = zero;
  float m_run = -3.0e38f, l_run = 0.f;

  const int nt = CAUSAL ? ((q0 + 47) >> 5) : (S_ / 32);
  for (int it = 0; it < nt; ++it) {
    const int kv0 = it * 32;
    // K as A-fragment: rows kv0+l15 (s0) and kv0+16+l15 (s1)
    const ushort_t* kr0 = Kp + (size_t)(kv0 + l15) * 768 + kslot * 8;
    v4f s0 = zero, s1 = zero;
#pragma unroll
    for (int ks = 0; ks < 8; ++ks) {
      v8bf k0 = *(const v8bf*)(kr0 + ks * 32);
      v8bf k1 = *(const v8bf*)(kr0 + 16 * 768 + ks * 32);
      s0 = __builtin_amdgcn_mfma_f32_16x16x32_bf16(k0, qf[ks], s0, 0, 0, 0);
      s1 = __builtin_amdgcn_mfma_f32_16x16x32_bf16(k1, qf[ks], s1, 0, 0, 0);
    }
    // s_n[i] = score(q = q0+l15, kv = kv0 + n*16 + kslot*4 + i)
    float ps[2][4];
#pragma unroll
    for (int i = 0; i < 4; ++i) { ps[0][i] = s0[i] * 0.0625f; ps[1][i] = s1[i] * 0.0625f; }
    if (CAUSAL && kv0 + 31 > q) {
#pragma unroll
      for (int n = 0; n < 2; ++n)
#pragma unroll
        for (int i = 0; i < 4; ++i)
          if (kv0 + n * 16 + kslot * 4 + i > q) ps[n][i] = -3.0e38f;
    }
    // online softmax; row q is lane-local in l15, spread over kslot (bits 4-5)
    float mx = ps[0][0];
#pragma unroll
    for (int i = 1; i < 4; ++i) mx = fmaxf(mx, ps[0][i]);
#pragma unroll
    for (int i = 0; i < 4; ++i) mx = fmaxf(mx, ps[1][i]);
    mx = fmaxf(mx, __shfl_xor(mx, 16));
    mx = fmaxf(mx, __shfl_xor(mx, 32));
    float mn = fmaxf(m_run, mx);
    float al = __expf(m_run - mn);
    float pe[2][4]; float lt = 0.f;
#pragma unroll
    for (int n = 0; n < 2; ++n)
#pragma unroll
      for (int i = 0; i < 4; ++i) { pe[n][i] = __expf(ps[n][i] - mn); lt += pe[n][i]; }
    lt += __shfl_xor(lt, 16);
    lt += __shfl_xor(lt, 32);
    l_run = l_run * al + lt;
    m_run = mn;
    // pack P to bf16 pairs; redistribute so lane (G=kslot, l15) holds
    // P[q=l15][kv = G*8 + j], j=0..7.  Sources: lane ((2G+b)&3, l15),
    // reg-set n = G>>1.  (traced for G=0..3: kv order exact)
    unsigned P0 = (unsigned)f2bf(pe[0][0]) | ((unsigned)f2bf(pe[0][1]) << 16);
    unsigned P1 = (unsigned)f2bf(pe[0][2]) | ((unsigned)f2bf(pe[0][3]) << 16);
    unsigned P2 = (unsigned)f2bf(pe[1][0]) | ((unsigned)f2bf(pe[1][1]) << 16);
    unsigned P3 = (unsigned)f2bf(pe[1][2]) | ((unsigned)f2bf(pe[1][3]) << 16);
    int srcLo = (((kslot * 2) & 3) << 4) | l15;
    int srcHi = (((kslot * 2 + 1) & 3) << 4) | l15;
    int a0 = __shfl((int)P0, srcLo), a1 = __shfl((int)P1, srcLo);
    int a2 = __shfl((int)P2, srcLo), a3 = __shfl((int)P3, srcLo);
    int b0 = __shfl((int)P0, srcHi), b1 = __shfl((int)P1, srcHi);
    int b2 = __shfl((int)P2, srcHi), b3 = __shfl((int)P3, srcHi);
    union { unsigned u[4]; v8bf v; } pbu;
    pbu.u[0] = (unsigned)(kslot < 2 ? a0 : a2);
    pbu.u[1] = (unsigned)(kslot < 2 ? a1 : a3);
    pbu.u[2] = (unsigned)(kslot < 2 ? b0 : b2);
    pbu.u[3] = (unsigned)(kslot < 2 ? b1 : b3);
    v8bf pb = pbu.v;
    // rescale (alpha lane-local: acc col = q = l15) then PV accumulate
#pragma unroll
    for (int td = 0; td < 16; ++td) acc_o[td] *= al;
    const ushort_t* vr = Vb + (size_t)l15 * S_ + kv0 + kslot * 8;
#pragma unroll
    for (int td = 0; td < 16; ++td) {
      v8bf vf = *(const v8bf*)(vr + (size_t)td * 16 * S_);   // V^T row td*16+l15
      acc_o[td] = __builtin_amdgcn_mfma_f32_16x16x32_bf16(vf, pb, acc_o[td], 0, 0, 0);
    }
  }
  float li = 1.f / l_run;
  float* orow = O + ((size_t)b * T_ + q) * D_ + kslot * 4;
#pragma unroll
  for (int td = 0; td < 16; ++td) {
    float4 v;
    v.x = acc_o[td][0] * li; v.y = acc_o[td][1] * li;
    v.z = acc_o[td][2] * li; v.w = acc_o[td][3] * li;
    *(float4*)(orow + td * 16) = v;
  }
}

// ---------------------------------------------------------------------------
// out = LN(base + delta) * g + be; writes fp32 (residual) and optional bf16.
// ---------------------------------------------------------------------------
__global__ __launch_bounds__(256) void add_ln_k(
    const float* __restrict__ base, const float* __restrict__ delta,
    const float* __restrict__ g, const float* __restrict__ be,
    float* __restrict__ outf, ushort_t* __restrict__ outb) {
  int row = blockIdx.x * 4 + (threadIdx.x >> 6);
  int lane = threadIdx.x & 63;
  size_t off = (size_t)row * 256 + lane * 4;
  float4 xv = *(const float4*)(base + off);
  float4 dv = *(const float4*)(delta + off);
  float s0 = xv.x + dv.x, s1 = xv.y + dv.y, s2 = xv.z + dv.z, s3 = xv.w + dv.w;
  float sum = s0 + s1 + s2 + s3;
  for (int mk = 1; mk < 64; mk <<= 1) sum += __shfl_xor(sum, mk);
  float mean = sum * (1.f / 256.f);
  float e0 = s0 - mean, e1 = s1 - mean, e2 = s2 - mean, e3 = s3 - mean;
  float ss = e0 * e0 + e1 * e1 + e2 * e2 + e3 * e3;
  for (int mk = 1; mk < 64; mk <<= 1) ss += __shfl_xor(ss, mk);
  float rstd = rsqrtf(ss * (1.f / 256.f) + 1e-5f);
  float4 gv = *(const float4*)(g + lane * 4);
  float4 bv = *(const float4*)(be + lane * 4);
  float o0 = e0 * rstd * gv.x + bv.x, o1 = e1 * rstd * gv.y + bv.y;
  float o2 = e2 * rstd * gv.z + bv.z, o3 = e3 * rstd * gv.w + bv.w;
  float4 ov; ov.x = o0; ov.y = o1; ov.z = o2; ov.w = o3;
  *(float4*)(outf + off) = ov;
  if (outb) {
    union { ushort_t u[4]; uint2 v; } pk;
    pk.u[0] = f2bf(o0); pk.u[1] = f2bf(o1); pk.u[2] = f2bf(o2); pk.u[3] = f2bf(o3);
    *(uint2*)(outb + off) = pk.v;
  }
}

// ---------------------------------------------------------------------------
extern "C" void kernel_launch(void* const* d_in, const int* in_sizes, int n_in,
                              void* d_out, int out_size, void* d_ws, size_t ws_size,
                              hipStream_t stream) {
  const float* y   = (const float*)d_in[0];
  const float* Z   = (const float*)d_in[1];
  const float* Wq1 = (const float*)d_in[3];  const float* bq1 = (const float*)d_in[4];
  const float* Wk1 = (const float*)d_in[5];  const float* bk1 = (const float*)d_in[6];
  const float* Wv1 = (const float*)d_in[7];  const float* bv1 = (const float*)d_in[8];
  const float* Wq2 = (const float*)d_in[9];  const float* bq2 = (const float*)d_in[10];
  const float* Wk2 = (const float*)d_in[11]; const float* bk2 = (const float*)d_in[12];
  const float* Wv2 = (const float*)d_in[13]; const float* bv2 = (const float*)d_in[14];
  const float* W1  = (const float*)d_in[15]; const float* b1  = (const float*)d_in[16];
  const float* W2  = (const float*)d_in[17]; const float* b2  = (const float*)d_in[18];
  const float* g1  = (const float*)d_in[19]; const float* be1 = (const float*)d_in[20];
  const float* g2  = (const float*)d_in[21]; const float* be2 = (const float*)d_in[22];
  const float* g3  = (const float*)d_in[23]; const float* be3 = (const float*)d_in[24];
  float* out = (float*)d_out;

  char* p = (char*)d_ws;
  auto alloc = [&](size_t sz) { char* r = p; p += (sz + 255) & ~(size_t)255; return r; };
  const size_t NBT = (size_t)B_ * T_ * D_;   // 2,097,152 elems
  ushort_t* Wq1t = (ushort_t*)alloc(D_ * D_ * 2);
  ushort_t* Wk1t = (ushort_t*)alloc(D_ * D_ * 2);
  ushort_t* Wv1t = (ushort_t*)alloc(D_ * D_ * 2);
  ushort_t* Wq2t = (ushort_t*)alloc(D_ * D_ * 2);
  ushort_t* Wk2t = (ushort_t*)alloc(D_ * D_ * 2);
  ushort_t* Wv2t = (ushort_t*)alloc(D_ * D_ * 2);
  ushort_t* W1t  = (ushort_t*)alloc((size_t)F_ * D_ * 2);
  ushort_t* W2t  = (ushort_t*)alloc((size_t)D_ * F_ * 2);
  float* bqkv1 = (float*)alloc(768 * 4);
  float* bkv2  = (float*)alloc(512 * 4);
  ushort_t* yb  = (ushort_t*)alloc(NBT * 2);
  ushort_t* Zb  = (ushort_t*)alloc(NBT * 2);
  float*    y1f = (float*)alloc(NBT * 4);
  ushort_t* y1b = (ushort_t*)alloc(NBT * 2);
  float*    y2f = (float*)alloc(NBT * 4);
  ushort_t* y2b = (ushort_t*)alloc(NBT * 2);
  ushort_t* QKVb = (ushort_t*)alloc((size_t)B_ * T_ * 768 * 2);  // [8192,768]
  ushort_t* Vt   = (ushort_t*)alloc(NBT * 2);                    // [B][D][S]
  ushort_t* Hb = QKVb;   // FFN hidden [8192,1024] aliases QKVb+Vt (16MB exact)
  float* tmp = (float*)alloc(NBT * 4);

  // --- prep ---
  WP8 wp;
  wp.m[0] = {Wq1, Wq1t, D_, D_}; wp.m[1] = {Wk1, Wk1t, D_, D_};
  wp.m[2] = {Wv1, Wv1t, D_, D_}; wp.m[3] = {Wq2, Wq2t, D_, D_};
  wp.m[4] = {Wk2, Wk2t, D_, D_}; wp.m[5] = {Wv2, Wv2t, D_, D_};
  wp.m[6] = {W1, W1t, D_, F_};   wp.m[7] = {W2, W2t, F_, D_};
  prep_weights_k<<<dim3(16, 16, 8), dim3(64, 4), 0, stream>>>(wp);
  pack_bias_k<<<dim3(5), 256, 0, stream>>>(bq1, bk1, bv1, bk2, bv2, bqkv1, bkv2);
  cvt_k<<<dim3((int)(NBT / 8 / 256), 2), 256, 0, stream>>>(y, yb, Z, Zb);

  auto gemm = [&](const ushort_t* A, int lda, const ushort_t* Bt, int ldb,
                  const float* bias, float* Cf, ushort_t* Cb, int ldc,
                  int M, int N, int K, bool relu) {
    dim3 g(N / 64, M / 128, 1);
    if (relu)
      gemm_bt<true><<<g, 256, 0, stream>>>(A, lda, Bt, ldb, bias, Cf, Cb, ldc, K);
    else
      gemm_bt<false><<<g, 256, 0, stream>>>(A, lda, Bt, ldb, bias, Cf, Cb, ldc, K);
  };

  auto attention = [&](float* attout, int causal) {
    transpose_bf16_k<<<dim3(S_ / 64, D_ / 64, B_), dim3(64, 4), 0, stream>>>(
        QKVb + 512, (long long)S_ * 768, 768, Vt, (long long)D_ * S_, S_, D_);
    if (causal)
      flash_k<1><<<dim3(T_ / 16, B_), 64, 0, stream>>>(QKVb, Vt, attout);
    else
      flash_k<0><<<dim3(T_ / 16, B_), 64, 0, stream>>>(QKVb, Vt, attout);
  };

  // --- self-attention ---
  gemm(yb, D_, Wq1t, D_, bqkv1, nullptr, QKVb, 768, B_ * T_, 768, D_, false);
  attention(tmp, 1);
  add_ln_k<<<dim3(B_ * T_ / 4), 256, 0, stream>>>(y, tmp, g1, be1, y1f, y1b);

  // --- cross-attention ---
  gemm(y1b, D_, Wq2t, D_, bq2, nullptr, QKVb, 768, B_ * T_, D_, D_, false);
  gemm(Zb, D_, Wk2t, D_, bkv2, nullptr, QKVb + 256, 768, B_ * S_, 512, D_, false);
  attention(tmp, 0);
  add_ln_k<<<dim3(B_ * T_ / 4), 256, 0, stream>>>(y1f, tmp, g2, be2, y2f, y2b);

  // --- FFN ---
  gemm(y2b, D_, W1t, D_, b1, nullptr, Hb, F_, B_ * T_, F_, D_, true);
  gemm(Hb, F_, W2t, F_, b2, tmp, nullptr, D_, B_ * T_, D_, F_, false);
  add_ln_k<<<dim3(B_ * T_ / 4), 256, 0, stream>>>(y2f, tmp, g3, be3, out, nullptr);
}

// Round 6
// 451.063 us; speedup vs baseline: 1.2766x; 1.2766x over previous
//
#include <hip/hip_runtime.h>

#define B_ 4
#define T_ 2048
#define S_ 2048
#define D_ 256
#define F_ 1024

typedef unsigned short ushort_t;
typedef __bf16 v8bf __attribute__((ext_vector_type(8)));
typedef float v4f __attribute__((ext_vector_type(4)));
typedef __attribute__((address_space(1))) const unsigned int gas_uint;
typedef __attribute__((address_space(3))) unsigned int las_uint;

__device__ __forceinline__ ushort_t f2bf(float f) {
  unsigned u = __float_as_uint(f);
  unsigned r = (u + 0x7FFFu + ((u >> 16) & 1u)) >> 16;   // RTNE
  return (ushort_t)r;
}

// ---------------------------------------------------------------------------
// Weight prep: fp32 [K,N] -> bf16 [N,K] (transpose + convert), 8 matrices.
// ---------------------------------------------------------------------------
struct WP { const float* s; ushort_t* d; int K, N; };
struct WP8 { WP m[8]; };

__global__ void prep_weights_k(WP8 a) {
  WP w = a.m[blockIdx.z];
  int k0 = blockIdx.x * 64, n0 = blockIdx.y * 64;
  if (k0 >= w.K || n0 >= w.N) return;
  __shared__ ushort_t tile[64][65];
  int tx = threadIdx.x, ty = threadIdx.y;
  for (int r = ty; r < 64; r += 4)
    tile[r][tx] = f2bf(w.s[(size_t)(k0 + r) * w.N + n0 + tx]);
  __syncthreads();
  for (int r = ty; r < 64; r += 4)
    w.d[(size_t)(n0 + r) * w.K + k0 + tx] = tile[tx][r];
}

// pack biases: bqkv1 = [bq1|bk1|bv1] (768), bkv2 = [bk2|bv2] (512)
__global__ void pack_bias_k(const float* bq1, const float* bk1, const float* bv1,
                            const float* bk2, const float* bv2,
                            float* bqkv1, float* bkv2) {
  int t = blockIdx.x * 256 + threadIdx.x;
  if (t < 768) bqkv1[t] = (t < 256) ? bq1[t] : (t < 512) ? bk1[t - 256] : bv1[t - 512];
  if (t < 512) bkv2[t] = (t < 256) ? bk2[t] : bv2[t - 256];
}

// fp32 -> bf16 elementwise for y and Z (grid.y selects tensor)
__global__ void cvt_k(const float* __restrict__ a, ushort_t* __restrict__ oa,
                      const float* __restrict__ b, ushort_t* __restrict__ ob) {
  int i = blockIdx.x * 256 + threadIdx.x;
  const float* s = blockIdx.y ? b : a;
  ushort_t* d = blockIdx.y ? ob : oa;
  size_t off = (size_t)i * 8;
  float4 v0 = *(const float4*)(s + off);
  float4 v1 = *(const float4*)(s + off + 4);
  union { ushort_t u[8]; uint4 v; } pk;
  pk.u[0] = f2bf(v0.x); pk.u[1] = f2bf(v0.y); pk.u[2] = f2bf(v0.z); pk.u[3] = f2bf(v0.w);
  pk.u[4] = f2bf(v1.x); pk.u[5] = f2bf(v1.y); pk.u[6] = f2bf(v1.z); pk.u[7] = f2bf(v1.w);
  *(uint4*)(d + off) = pk.v;
}

// bf16 [rows,cols] (row stride ldin, batch stride sIz) -> bf16 [cols,rows]
__global__ void transpose_bf16_k(const ushort_t* __restrict__ in, long long sIz, int ldin,
                                 ushort_t* __restrict__ out, long long sOz,
                                 int rows, int cols) {
  in  += (size_t)blockIdx.z * sIz;
  out += (size_t)blockIdx.z * sOz;
  __shared__ ushort_t tile[64][65];
  int r0 = blockIdx.x * 64, c0 = blockIdx.y * 64;
  int tx = threadIdx.x, ty = threadIdx.y;
  for (int r = ty; r < 64; r += 4)
    tile[r][tx] = in[(size_t)(r0 + r) * ldin + c0 + tx];
  __syncthreads();
  for (int r = ty; r < 64; r += 4)
    out[(size_t)(c0 + r) * rows + r0 + tx] = tile[tx][r];
}

// ---------------------------------------------------------------------------
// GEMM: C[M,N] = A[M,K] @ Bt[N,K]^T + bias (projections + FFN).  Verified.
// ---------------------------------------------------------------------------
template<bool RELU>
__global__ __launch_bounds__(256, 2) void gemm_bt(
    const ushort_t* __restrict__ A, int lda,
    const ushort_t* __restrict__ Bt, int ldb,
    const float* __restrict__ bias,
    float* __restrict__ Cf, ushort_t* __restrict__ Cb, int ldc, int K) {
  const int n0 = blockIdx.x * 64, m0 = blockIdx.y * 128;
  const int t = threadIdx.x, lane = t & 63, wv = t >> 6;
  const int wm = wv >> 1, wn = wv & 1;
  const int kslot = lane >> 4, l15 = lane & 15;
  __shared__ __align__(16) char smem[24576];   // A 16KB + B 8KB
  char* sA = smem;
  char* sB = smem + 16384;

  v4f acc[4][2];
  v4f zero = {0.f, 0.f, 0.f, 0.f};
#pragma unroll
  for (int m = 0; m < 4; ++m)
#pragma unroll
    for (int n = 0; n < 2; ++n) acc[m][n] = zero;

  for (int kk = 0; kk < K; kk += 64) {
    __syncthreads();
#pragma unroll
    for (int q = 0; q < 4; ++q) {
      int g = q * 256 + t;
      int row = g >> 3, j = g & 7;
      const ushort_t* src = A + (long long)(m0 + row) * lda + kk + ((j ^ (row & 7)) << 3);
      __builtin_amdgcn_global_load_lds((gas_uint*)src,
          (las_uint*)(sA + q * 4096 + (wv << 10)), 16, 0, 0);
    }
#pragma unroll
    for (int q = 0; q < 2; ++q) {
      int g = q * 256 + t;
      int row = g >> 3, j = g & 7;
      const ushort_t* src = Bt + (long long)(n0 + row) * ldb + kk + ((j ^ (row & 7)) << 3);
      __builtin_amdgcn_global_load_lds((gas_uint*)src,
          (las_uint*)(sB + q * 4096 + (wv << 10)), 16, 0, 0);
    }
    __syncthreads();
#pragma unroll
    for (int ks = 0; ks < 2; ++ks) {
      v8bf af[4]; v8bf bfr[2];
#pragma unroll
      for (int m = 0; m < 4; ++m) {
        int row = wm * 64 + m * 16 + l15;
        int gs = (ks * 4 + kslot) ^ (row & 7);
        af[m] = *(const v8bf*)(sA + ((row * 8 + gs) << 4));
      }
#pragma unroll
      for (int n = 0; n < 2; ++n) {
        int row = wn * 32 + n * 16 + l15;
        int gs = (ks * 4 + kslot) ^ (row & 7);
        bfr[n] = *(const v8bf*)(sB + ((row * 8 + gs) << 4));
      }
#pragma unroll
      for (int m = 0; m < 4; ++m)
#pragma unroll
        for (int n = 0; n < 2; ++n)
          acc[m][n] = __builtin_amdgcn_mfma_f32_16x16x32_bf16(af[m], bfr[n], acc[m][n], 0, 0, 0);
    }
  }
#pragma unroll
  for (int m = 0; m < 4; ++m) {
    int grow0 = m0 + wm * 64 + m * 16 + (kslot << 2);
#pragma unroll
    for (int n = 0; n < 2; ++n) {
      int gcol = n0 + wn * 32 + n * 16 + l15;
      float bb = bias ? bias[gcol] : 0.f;
#pragma unroll
      for (int i = 0; i < 4; ++i) {
        float v = acc[m][n][i] + bb;
        if (RELU) v = fmaxf(v, 0.f);
        long long off = (long long)(grow0 + i) * ldc + gcol;
        if (Cf) Cf[off] = v;
        if (Cb) Cb[off] = f2bf(v);
      }
    }
  }
}

// ---------------------------------------------------------------------------
// Flash attention, split-KV.  4 waves per block, each wave = the verified
// round-5 one-wave loop over KV tiles it = w, w+4, ... (own m/l/acc partials),
// then a flash merge in LDS: stats -> m_tot/l_tot, scale by exp(m_w-m_tot),
// pairwise accumulate (2 serial passes), normalized final write.
// Per-wave inner loop is byte-identical to the round-5 PASSING kernel.
// ---------------------------------------------------------------------------
template<int CAUSAL>
__global__ __launch_bounds__(256) void flash_k(
    const ushort_t* __restrict__ QKV, const ushort_t* __restrict__ Vt,
    float* __restrict__ O) {
  const int b = blockIdx.y, q0 = blockIdx.x * 16;
  const int t = threadIdx.x, w = t >> 6, lane = t & 63;
  const int kslot = lane >> 4, l15 = lane & 15;
  const ushort_t* Qp = QKV + (size_t)b * T_ * 768;
  const ushort_t* Kp = Qp + 256;
  const ushort_t* Vb = Vt + (size_t)b * (size_t)D_ * S_;
  const int q = q0 + l15;

  __shared__ float sAccA[16 * 260];   // [q][260] padded (bank spread)
  __shared__ float sAccB[16 * 260];
  __shared__ float sM[4][16], sL[4][16], sInv[16];

  // Q as B-fragment: row q (via l15), k = ks*32 + kslot*8 + j
  v8bf qf[8];
  {
    const ushort_t* qrow = Qp + (size_t)q * 768 + kslot * 8;
#pragma unroll
    for (int ks = 0; ks < 8; ++ks) qf[ks] = *(const v8bf*)(qrow + ks * 32);
  }
  v4f acc_o[16];
  v4f zero = {0.f, 0.f, 0.f, 0.f};
#pragma unroll
  for (int td = 0; td < 16; ++td) acc_o[td] = zero;
  float m_run = -3.0e38f, l_run = 0.f;

  const int nt = CAUSAL ? ((q0 + 47) >> 5) : (S_ / 32);
  for (int it = w; it < nt; it += 4) {
    const int kv0 = it * 32;
    const ushort_t* kr0 = Kp + (size_t)(kv0 + l15) * 768 + kslot * 8;
    v4f s0 = zero, s1 = zero;
#pragma unroll
    for (int ks = 0; ks < 8; ++ks) {
      v8bf k0 = *(const v8bf*)(kr0 + ks * 32);
      v8bf k1 = *(const v8bf*)(kr0 + 16 * 768 + ks * 32);
      s0 = __builtin_amdgcn_mfma_f32_16x16x32_bf16(k0, qf[ks], s0, 0, 0, 0);
      s1 = __builtin_amdgcn_mfma_f32_16x16x32_bf16(k1, qf[ks], s1, 0, 0, 0);
    }
    float ps[2][4];
#pragma unroll
    for (int i = 0; i < 4; ++i) { ps[0][i] = s0[i] * 0.0625f; ps[1][i] = s1[i] * 0.0625f; }
    if (CAUSAL && kv0 + 31 > q) {
#pragma unroll
      for (int n = 0; n < 2; ++n)
#pragma unroll
        for (int i = 0; i < 4; ++i)
          if (kv0 + n * 16 + kslot * 4 + i > q) ps[n][i] = -3.0e38f;
    }
    float mx = ps[0][0];
#pragma unroll
    for (int i = 1; i < 4; ++i) mx = fmaxf(mx, ps[0][i]);
#pragma unroll
    for (int i = 0; i < 4; ++i) mx = fmaxf(mx, ps[1][i]);
    mx = fmaxf(mx, __shfl_xor(mx, 16));
    mx = fmaxf(mx, __shfl_xor(mx, 32));
    float mn = fmaxf(m_run, mx);
    float al = __expf(m_run - mn);
    float pe[2][4]; float lt = 0.f;
#pragma unroll
    for (int n = 0; n < 2; ++n)
#pragma unroll
      for (int i = 0; i < 4; ++i) { pe[n][i] = __expf(ps[n][i] - mn); lt += pe[n][i]; }
    lt += __shfl_xor(lt, 16);
    lt += __shfl_xor(lt, 32);
    l_run = l_run * al + lt;
    m_run = mn;
    unsigned P0 = (unsigned)f2bf(pe[0][0]) | ((unsigned)f2bf(pe[0][1]) << 16);
    unsigned P1 = (unsigned)f2bf(pe[0][2]) | ((unsigned)f2bf(pe[0][3]) << 16);
    unsigned P2 = (unsigned)f2bf(pe[1][0]) | ((unsigned)f2bf(pe[1][1]) << 16);
    unsigned P3 = (unsigned)f2bf(pe[1][2]) | ((unsigned)f2bf(pe[1][3]) << 16);
    int srcLo = (((kslot * 2) & 3) << 4) | l15;
    int srcHi = (((kslot * 2 + 1) & 3) << 4) | l15;
    int a0 = __shfl((int)P0, srcLo), a1 = __shfl((int)P1, srcLo);
    int a2 = __shfl((int)P2, srcLo), a3 = __shfl((int)P3, srcLo);
    int b0 = __shfl((int)P0, srcHi), b1 = __shfl((int)P1, srcHi);
    int b2 = __shfl((int)P2, srcHi), b3 = __shfl((int)P3, srcHi);
    union { unsigned u[4]; v8bf v; } pbu;
    pbu.u[0] = (unsigned)(kslot < 2 ? a0 : a2);
    pbu.u[1] = (unsigned)(kslot < 2 ? a1 : a3);
    pbu.u[2] = (unsigned)(kslot < 2 ? b0 : b2);
    pbu.u[3] = (unsigned)(kslot < 2 ? b1 : b3);
    v8bf pb = pbu.v;
#pragma unroll
    for (int td = 0; td < 16; ++td) acc_o[td] *= al;
    const ushort_t* vr = Vb + (size_t)l15 * S_ + kv0 + kslot * 8;
#pragma unroll
    for (int td = 0; td < 16; ++td) {
      v8bf vf = *(const v8bf*)(vr + (size_t)td * 16 * S_);   // V^T row td*16+l15
      acc_o[td] = __builtin_amdgcn_mfma_f32_16x16x32_bf16(vf, pb, acc_o[td], 0, 0, 0);
    }
  }

  // ---- cross-wave flash merge ----
  if (kslot == 0) { sM[w][l15] = m_run; sL[w][l15] = l_run; }
  __syncthreads();
  float m0v = sM[0][l15], m1v = sM[1][l15], m2v = sM[2][l15], m3v = sM[3][l15];
  float m_tot = fmaxf(fmaxf(m0v, m1v), fmaxf(m2v, m3v));
  float l_tot = sL[0][l15] * __expf(m0v - m_tot) + sL[1][l15] * __expf(m1v - m_tot)
              + sL[2][l15] * __expf(m2v - m_tot) + sL[3][l15] * __expf(m3v - m_tot);
  if (w == 0 && kslot == 0) sInv[l15] = 1.f / l_tot;
  float mysc = __expf(m_run - m_tot);
#pragma unroll
  for (int td = 0; td < 16; ++td) acc_o[td] *= mysc;
  float* dst = ((w & 2) ? sAccB : sAccA) + l15 * 260 + kslot * 4;
  if ((w & 1) == 0) {
#pragma unroll
    for (int td = 0; td < 16; ++td) *(v4f*)(dst + td * 16) = acc_o[td];
  }
  __syncthreads();
  if (w & 1) {
#pragma unroll
    for (int td = 0; td < 16; ++td) {
      v4f o = *(const v4f*)(dst + td * 16);
      o += acc_o[td];
      *(v4f*)(dst + td * 16) = o;
    }
  }
  __syncthreads();
  // final write: thread t -> q row t>>4, d block (t&15)*16
  {
    int qr = t >> 4, dc = (t & 15) * 16;
    float inv = sInv[qr];
    const float* pa = sAccA + qr * 260 + dc;
    const float* pb2 = sAccB + qr * 260 + dc;
    float* op = O + ((size_t)b * T_ + q0 + qr) * D_ + dc;
#pragma unroll
    for (int j = 0; j < 4; ++j) {
      v4f va = *(const v4f*)(pa + j * 4);
      v4f vb2 = *(const v4f*)(pb2 + j * 4);
      v4f vo = va + vb2;
      vo *= inv;
      *(v4f*)(op + j * 4) = vo;
    }
  }
}

// ---------------------------------------------------------------------------
// out = LN(base + delta) * g + be; writes fp32 (residual) and optional bf16.
// ---------------------------------------------------------------------------
__global__ __launch_bounds__(256) void add_ln_k(
    const float* __restrict__ base, const float* __restrict__ delta,
    const float* __restrict__ g, const float* __restrict__ be,
    float* __restrict__ outf, ushort_t* __restrict__ outb) {
  int row = blockIdx.x * 4 + (threadIdx.x >> 6);
  int lane = threadIdx.x & 63;
  size_t off = (size_t)row * 256 + lane * 4;
  float4 xv = *(const float4*)(base + off);
  float4 dv = *(const float4*)(delta + off);
  float s0 = xv.x + dv.x, s1 = xv.y + dv.y, s2 = xv.z + dv.z, s3 = xv.w + dv.w;
  float sum = s0 + s1 + s2 + s3;
  for (int mk = 1; mk < 64; mk <<= 1) sum += __shfl_xor(sum, mk);
  float mean = sum * (1.f / 256.f);
  float e0 = s0 - mean, e1 = s1 - mean, e2 = s2 - mean, e3 = s3 - mean;
  float ss = e0 * e0 + e1 * e1 + e2 * e2 + e3 * e3;
  for (int mk = 1; mk < 64; mk <<= 1) ss += __shfl_xor(ss, mk);
  float rstd = rsqrtf(ss * (1.f / 256.f) + 1e-5f);
  float4 gv = *(const float4*)(g + lane * 4);
  float4 bv = *(const float4*)(be + lane * 4);
  float o0 = e0 * rstd * gv.x + bv.x, o1 = e1 * rstd * gv.y + bv.y;
  float o2 = e2 * rstd * gv.z + bv.z, o3 = e3 * rstd * gv.w + bv.w;
  float4 ov; ov.x = o0; ov.y = o1; ov.z = o2; ov.w = o3;
  *(float4*)(outf + off) = ov;
  if (outb) {
    union { ushort_t u[4]; uint2 v; } pk;
    pk.u[0] = f2bf(o0); pk.u[1] = f2bf(o1); pk.u[2] = f2bf(o2); pk.u[3] = f2bf(o3);
    *(uint2*)(outb + off) = pk.v;
  }
}

// ---------------------------------------------------------------------------
extern "C" void kernel_launch(void* const* d_in, const int* in_sizes, int n_in,
                              void* d_out, int out_size, void* d_ws, size_t ws_size,
                              hipStream_t stream) {
  const float* y   = (const float*)d_in[0];
  const float* Z   = (const float*)d_in[1];
  const float* Wq1 = (const float*)d_in[3];  const float* bq1 = (const float*)d_in[4];
  const float* Wk1 = (const float*)d_in[5];  const float* bk1 = (const float*)d_in[6];
  const float* Wv1 = (const float*)d_in[7];  const float* bv1 = (const float*)d_in[8];
  const float* Wq2 = (const float*)d_in[9];  const float* bq2 = (const float*)d_in[10];
  const float* Wk2 = (const float*)d_in[11]; const float* bk2 = (const float*)d_in[12];
  const float* Wv2 = (const float*)d_in[13]; const float* bv2 = (const float*)d_in[14];
  const float* W1  = (const float*)d_in[15]; const float* b1  = (const float*)d_in[16];
  const float* W2  = (const float*)d_in[17]; const float* b2  = (const float*)d_in[18];
  const float* g1  = (const float*)d_in[19]; const float* be1 = (const float*)d_in[20];
  const float* g2  = (const float*)d_in[21]; const float* be2 = (const float*)d_in[22];
  const float* g3  = (const float*)d_in[23]; const float* be3 = (const float*)d_in[24];
  float* out = (float*)d_out;

  char* p = (char*)d_ws;
  auto alloc = [&](size_t sz) { char* r = p; p += (sz + 255) & ~(size_t)255; return r; };
  const size_t NBT = (size_t)B_ * T_ * D_;   // 2,097,152 elems
  ushort_t* Wq1t = (ushort_t*)alloc(D_ * D_ * 2);
  ushort_t* Wk1t = (ushort_t*)alloc(D_ * D_ * 2);
  ushort_t* Wv1t = (ushort_t*)alloc(D_ * D_ * 2);
  ushort_t* Wq2t = (ushort_t*)alloc(D_ * D_ * 2);
  ushort_t* Wk2t = (ushort_t*)alloc(D_ * D_ * 2);
  ushort_t* Wv2t = (ushort_t*)alloc(D_ * D_ * 2);
  ushort_t* W1t  = (ushort_t*)alloc((size_t)F_ * D_ * 2);
  ushort_t* W2t  = (ushort_t*)alloc((size_t)D_ * F_ * 2);
  float* bqkv1 = (float*)alloc(768 * 4);
  float* bkv2  = (float*)alloc(512 * 4);
  ushort_t* yb  = (ushort_t*)alloc(NBT * 2);
  ushort_t* Zb  = (ushort_t*)alloc(NBT * 2);
  float*    y1f = (float*)alloc(NBT * 4);
  ushort_t* y1b = (ushort_t*)alloc(NBT * 2);
  float*    y2f = (float*)alloc(NBT * 4);
  ushort_t* y2b = (ushort_t*)alloc(NBT * 2);
  ushort_t* QKVb = (ushort_t*)alloc((size_t)B_ * T_ * 768 * 2);  // [8192,768]
  ushort_t* Vt   = (ushort_t*)alloc(NBT * 2);                    // [B][D][S]
  ushort_t* Hb = QKVb;   // FFN hidden [8192,1024] aliases QKVb+Vt
  float* tmp = (float*)alloc(NBT * 4);

  // --- prep ---
  WP8 wp;
  wp.m[0] = {Wq1, Wq1t, D_, D_}; wp.m[1] = {Wk1, Wk1t, D_, D_};
  wp.m[2] = {Wv1, Wv1t, D_, D_}; wp.m[3] = {Wq2, Wq2t, D_, D_};
  wp.m[4] = {Wk2, Wk2t, D_, D_}; wp.m[5] = {Wv2, Wv2t, D_, D_};
  wp.m[6] = {W1, W1t, D_, F_};   wp.m[7] = {W2, W2t, F_, D_};
  prep_weights_k<<<dim3(16, 16, 8), dim3(64, 4), 0, stream>>>(wp);
  pack_bias_k<<<dim3(5), 256, 0, stream>>>(bq1, bk1, bv1, bk2, bv2, bqkv1, bkv2);
  cvt_k<<<dim3((int)(NBT / 8 / 256), 2), 256, 0, stream>>>(y, yb, Z, Zb);

  auto gemm = [&](const ushort_t* A, int lda, const ushort_t* Bt, int ldb,
                  const float* bias, float* Cf, ushort_t* Cb, int ldc,
                  int M, int N, int K, bool relu) {
    dim3 g(N / 64, M / 128, 1);
    if (relu)
      gemm_bt<true><<<g, 256, 0, stream>>>(A, lda, Bt, ldb, bias, Cf, Cb, ldc, K);
    else
      gemm_bt<false><<<g, 256, 0, stream>>>(A, lda, Bt, ldb, bias, Cf, Cb, ldc, K);
  };

  auto attention = [&](float* attout, int causal) {
    transpose_bf16_k<<<dim3(S_ / 64, D_ / 64, B_), dim3(64, 4), 0, stream>>>(
        QKVb + 512, (long long)S_ * 768, 768, Vt, (long long)D_ * S_, S_, D_);
    if (causal)
      flash_k<1><<<dim3(T_ / 16, B_), 256, 0, stream>>>(QKVb, Vt, attout);
    else
      flash_k<0><<<dim3(T_ / 16, B_), 256, 0, stream>>>(QKVb, Vt, attout);
  };

  // --- self-attention ---
  gemm(yb, D_, Wq1t, D_, bqkv1, nullptr, QKVb, 768, B_ * T_, 768, D_, false);
  attention(tmp, 1);
  add_ln_k<<<dim3(B_ * T_ / 4), 256, 0, stream>>>(y, tmp, g1, be1, y1f, y1b);

  // --- cross-attention ---
  gemm(y1b, D_, Wq2t, D_, bq2, nullptr, QKVb, 768, B_ * T_, D_, D_, false);
  gemm(Zb, D_, Wk2t, D_, bkv2, nullptr, QKVb + 256, 768, B_ * S_, 512, D_, false);
  attention(tmp, 0);
  add_ln_k<<<dim3(B_ * T_ / 4), 256, 0, stream>>>(y1f, tmp, g2, be2, y2f, y2b);

  // --- FFN ---
  gemm(y2b, D_, W1t, D_, b1, nullptr, Hb, F_, B_ * T_, F_, D_, true);
  gemm(Hb, F_, W2t, F_, b2, tmp, nullptr, D_, B_ * T_, D_, F_, false);
  add_ln_k<<<dim3(B_ * T_ / 4), 256, 0, stream>>>(y2f, tmp, g3, be3, out, nullptr);
}

// Round 7
// 343.267 us; speedup vs baseline: 1.6774x; 1.3140x over previous
//
#include <hip/hip_runtime.h>

#define B_ 4
#define T_ 2048
#define S_ 2048
#define D_ 256
#define F_ 1024

typedef unsigned short ushort_t;
typedef __bf16 v8bf __attribute__((ext_vector_type(8)));
typedef float v4f __attribute__((ext_vector_type(4)));
typedef __attribute__((address_space(1))) const unsigned int gas_uint;
typedef __attribute__((address_space(3))) unsigned int las_uint;

__device__ __forceinline__ ushort_t f2bf(float f) {
  unsigned u = __float_as_uint(f);
  unsigned r = (u + 0x7FFFu + ((u >> 16) & 1u)) >> 16;   // RTNE
  return (ushort_t)r;
}
__device__ __forceinline__ float bf2f(ushort_t u) {
  return __uint_as_float((unsigned)u << 16);
}

// ---------------------------------------------------------------------------
// Weight prep: fp32 [K,N] -> bf16 [N,K] (transpose + convert), 8 matrices.
// ---------------------------------------------------------------------------
struct WP { const float* s; ushort_t* d; int K, N; };
struct WP8 { WP m[8]; };

__global__ void prep_weights_k(WP8 a) {
  WP w = a.m[blockIdx.z];
  int k0 = blockIdx.x * 64, n0 = blockIdx.y * 64;
  if (k0 >= w.K || n0 >= w.N) return;
  __shared__ ushort_t tile[64][65];
  int tx = threadIdx.x, ty = threadIdx.y;
  for (int r = ty; r < 64; r += 4)
    tile[r][tx] = f2bf(w.s[(size_t)(k0 + r) * w.N + n0 + tx]);
  __syncthreads();
  for (int r = ty; r < 64; r += 4)
    w.d[(size_t)(n0 + r) * w.K + k0 + tx] = tile[tx][r];
}

// pack biases: bqkv1 = [bq1|bk1|bv1] (768), bkv2 = [bk2|bv2] (512)
__global__ void pack_bias_k(const float* bq1, const float* bk1, const float* bv1,
                            const float* bk2, const float* bv2,
                            float* bqkv1, float* bkv2) {
  int t = blockIdx.x * 256 + threadIdx.x;
  if (t < 768) bqkv1[t] = (t < 256) ? bq1[t] : (t < 512) ? bk1[t - 256] : bv1[t - 512];
  if (t < 512) bkv2[t] = (t < 256) ? bk2[t] : bv2[t - 256];
}

// fp32 -> bf16 elementwise for y and Z (grid.y selects tensor)
__global__ void cvt_k(const float* __restrict__ a, ushort_t* __restrict__ oa,
                      const float* __restrict__ b, ushort_t* __restrict__ ob) {
  int i = blockIdx.x * 256 + threadIdx.x;
  const float* s = blockIdx.y ? b : a;
  ushort_t* d = blockIdx.y ? ob : oa;
  size_t off = (size_t)i * 8;
  float4 v0 = *(const float4*)(s + off);
  float4 v1 = *(const float4*)(s + off + 4);
  union { ushort_t u[8]; uint4 v; } pk;
  pk.u[0] = f2bf(v0.x); pk.u[1] = f2bf(v0.y); pk.u[2] = f2bf(v0.z); pk.u[3] = f2bf(v0.w);
  pk.u[4] = f2bf(v1.x); pk.u[5] = f2bf(v1.y); pk.u[6] = f2bf(v1.z); pk.u[7] = f2bf(v1.w);
  *(uint4*)(d + off) = pk.v;
}

// bf16 [rows,cols] (row stride ldin, batch stride sIz) -> bf16 [cols,rows]
__global__ void transpose_bf16_k(const ushort_t* __restrict__ in, long long sIz, int ldin,
                                 ushort_t* __restrict__ out, long long sOz,
                                 int rows, int cols) {
  in  += (size_t)blockIdx.z * sIz;
  out += (size_t)blockIdx.z * sOz;
  __shared__ ushort_t tile[64][65];
  int r0 = blockIdx.x * 64, c0 = blockIdx.y * 64;
  int tx = threadIdx.x, ty = threadIdx.y;
  for (int r = ty; r < 64; r += 4)
    tile[r][tx] = in[(size_t)(r0 + r) * ldin + c0 + tx];
  __syncthreads();
  for (int r = ty; r < 64; r += 4)
    out[(size_t)(c0 + r) * rows + r0 + tx] = tile[tx][r];
}

// ---------------------------------------------------------------------------
// GEMM 128x64 tile (verified round 2/3): C = alpha*A@Bt^T + bias.
// causal: skip blocks fully above diagonal.  kcausal: K-loop to crow0+m0+128.
// ---------------------------------------------------------------------------
template<bool RELU>
__global__ __launch_bounds__(256, 2) void gemm_bt(
    const ushort_t* __restrict__ A, int lda, long long sAz,
    const ushort_t* __restrict__ Bt, int ldb, long long sBz,
    const float* __restrict__ bias,
    float* __restrict__ Cf, ushort_t* __restrict__ Cb, int ldc, long long sCz,
    int K, float alpha, int causal, int kcausal, int crow0) {
  const int n0 = blockIdx.x * 64, m0 = blockIdx.y * 128;
  if (causal && n0 > crow0 + m0 + 127) return;
  const int Keff = kcausal ? ((crow0 + m0 + 128 < K) ? crow0 + m0 + 128 : K) : K;
  A  += (long long)blockIdx.z * sAz;
  Bt += (long long)blockIdx.z * sBz;
  const long long coff = (long long)blockIdx.z * sCz;
  const int t = threadIdx.x, lane = t & 63, wv = t >> 6;
  const int wm = wv >> 1, wn = wv & 1;
  const int kslot = lane >> 4, l15 = lane & 15;
  __shared__ __align__(16) char smem[24576];   // A 16KB + B 8KB
  char* sA = smem;
  char* sB = smem + 16384;

  v4f acc[4][2];
  v4f zero = {0.f, 0.f, 0.f, 0.f};
#pragma unroll
  for (int m = 0; m < 4; ++m)
#pragma unroll
    for (int n = 0; n < 2; ++n) acc[m][n] = zero;

  for (int kk = 0; kk < Keff; kk += 64) {
    __syncthreads();
#pragma unroll
    for (int q = 0; q < 4; ++q) {
      int g = q * 256 + t;
      int row = g >> 3, j = g & 7;
      const ushort_t* src = A + (long long)(m0 + row) * lda + kk + ((j ^ (row & 7)) << 3);
      __builtin_amdgcn_global_load_lds((gas_uint*)src,
          (las_uint*)(sA + q * 4096 + (wv << 10)), 16, 0, 0);
    }
#pragma unroll
    for (int q = 0; q < 2; ++q) {
      int g = q * 256 + t;
      int row = g >> 3, j = g & 7;
      const ushort_t* src = Bt + (long long)(n0 + row) * ldb + kk + ((j ^ (row & 7)) << 3);
      __builtin_amdgcn_global_load_lds((gas_uint*)src,
          (las_uint*)(sB + q * 4096 + (wv << 10)), 16, 0, 0);
    }
    __syncthreads();
#pragma unroll
    for (int ks = 0; ks < 2; ++ks) {
      v8bf af[4]; v8bf bfr[2];
#pragma unroll
      for (int m = 0; m < 4; ++m) {
        int row = wm * 64 + m * 16 + l15;
        int gs = (ks * 4 + kslot) ^ (row & 7);
        af[m] = *(const v8bf*)(sA + ((row * 8 + gs) << 4));
      }
#pragma unroll
      for (int n = 0; n < 2; ++n) {
        int row = wn * 32 + n * 16 + l15;
        int gs = (ks * 4 + kslot) ^ (row & 7);
        bfr[n] = *(const v8bf*)(sB + ((row * 8 + gs) << 4));
      }
#pragma unroll
      for (int m = 0; m < 4; ++m)
#pragma unroll
        for (int n = 0; n < 2; ++n)
          acc[m][n] = __builtin_amdgcn_mfma_f32_16x16x32_bf16(af[m], bfr[n], acc[m][n], 0, 0, 0);
    }
  }
#pragma unroll
  for (int m = 0; m < 4; ++m) {
    int grow0 = m0 + wm * 64 + m * 16 + (kslot << 2);
#pragma unroll
    for (int n = 0; n < 2; ++n) {
      int gcol = n0 + wn * 32 + n * 16 + l15;
      float bb = bias ? bias[gcol] : 0.f;
#pragma unroll
      for (int i = 0; i < 4; ++i) {
        float v = acc[m][n][i] * alpha + bb;
        if (RELU) v = fmaxf(v, 0.f);
        long long off = coff + (long long)(grow0 + i) * ldc + gcol;
        if (Cf) Cf[off] = v;
        if (Cb) Cb[off] = f2bf(v);
      }
    }
  }
}

// ---------------------------------------------------------------------------
// GEMM 128x128 tile (m93/m97 ladder config: acc 4x4, BK=64, 4 waves 2x2,
// 32KB LDS).  Same staging/swizzle/fragment code paths as gemm_bt.
// ---------------------------------------------------------------------------
template<bool RELU>
__global__ __launch_bounds__(256, 2) void gemm_bt128(
    const ushort_t* __restrict__ A, int lda, long long sAz,
    const ushort_t* __restrict__ Bt, int ldb, long long sBz,
    const float* __restrict__ bias,
    float* __restrict__ Cf, ushort_t* __restrict__ Cb, int ldc, long long sCz,
    int K, float alpha, int causal, int crow0) {
  const int n0 = blockIdx.x * 128, m0 = blockIdx.y * 128;
  if (causal && n0 > crow0 + m0 + 127) return;
  A  += (long long)blockIdx.z * sAz;
  Bt += (long long)blockIdx.z * sBz;
  const long long coff = (long long)blockIdx.z * sCz;
  const int t = threadIdx.x, lane = t & 63, wv = t >> 6;
  const int wm = wv >> 1, wn = wv & 1;
  const int kslot = lane >> 4, l15 = lane & 15;
  __shared__ __align__(16) char smem[32768];   // A 16KB + B 16KB
  char* sA = smem;
  char* sB = smem + 16384;

  v4f acc[4][4];
  v4f zero = {0.f, 0.f, 0.f, 0.f};
#pragma unroll
  for (int m = 0; m < 4; ++m)
#pragma unroll
    for (int n = 0; n < 4; ++n) acc[m][n] = zero;

  for (int kk = 0; kk < K; kk += 64) {
    __syncthreads();
#pragma unroll
    for (int q = 0; q < 4; ++q) {
      int g = q * 256 + t;
      int row = g >> 3, j = g & 7;
      const ushort_t* src = A + (long long)(m0 + row) * lda + kk + ((j ^ (row & 7)) << 3);
      __builtin_amdgcn_global_load_lds((gas_uint*)src,
          (las_uint*)(sA + q * 4096 + (wv << 10)), 16, 0, 0);
    }
#pragma unroll
    for (int q = 0; q < 4; ++q) {
      int g = q * 256 + t;
      int row = g >> 3, j = g & 7;
      const ushort_t* src = Bt + (long long)(n0 + row) * ldb + kk + ((j ^ (row & 7)) << 3);
      __builtin_amdgcn_global_load_lds((gas_uint*)src,
          (las_uint*)(sB + q * 4096 + (wv << 10)), 16, 0, 0);
    }
    __syncthreads();
#pragma unroll
    for (int ks = 0; ks < 2; ++ks) {
      v8bf af[4]; v8bf bfr[4];
#pragma unroll
      for (int m = 0; m < 4; ++m) {
        int row = wm * 64 + m * 16 + l15;
        int gs = (ks * 4 + kslot) ^ (row & 7);
        af[m] = *(const v8bf*)(sA + ((row * 8 + gs) << 4));
      }
#pragma unroll
      for (int n = 0; n < 4; ++n) {
        int row = wn * 64 + n * 16 + l15;
        int gs = (ks * 4 + kslot) ^ (row & 7);
        bfr[n] = *(const v8bf*)(sB + ((row * 8 + gs) << 4));
      }
#pragma unroll
      for (int m = 0; m < 4; ++m)
#pragma unroll
        for (int n = 0; n < 4; ++n)
          acc[m][n] = __builtin_amdgcn_mfma_f32_16x16x32_bf16(af[m], bfr[n], acc[m][n], 0, 0, 0);
    }
  }
#pragma unroll
  for (int m = 0; m < 4; ++m) {
    int grow0 = m0 + wm * 64 + m * 16 + (kslot << 2);
#pragma unroll
    for (int n = 0; n < 4; ++n) {
      int gcol = n0 + wn * 64 + n * 16 + l15;
      float bb = bias ? bias[gcol] : 0.f;
#pragma unroll
      for (int i = 0; i < 4; ++i) {
        float v = acc[m][n][i] * alpha + bb;
        if (RELU) v = fmaxf(v, 0.f);
        long long off = coff + (long long)(grow0 + i) * ldc + gcol;
        if (Cf) Cf[off] = v;
        if (Cb) Cb[off] = f2bf(v);
      }
    }
  }
}

// ---------------------------------------------------------------------------
// Row softmax over S=2048 bf16 scores, in place.  Causal-trimmed: reads only
// cols < vlim (= row+1), writes zeros out to wlim (= PV's Keff boundary,
// 128-rounded), skips the rest entirely.
// ---------------------------------------------------------------------------
__global__ __launch_bounds__(256) void softmax_k(ushort_t* sc, int causal, int crow0) {
  int row = blockIdx.x;
  ushort_t* rp = sc + ((size_t)blockIdx.y * T_ + row) * S_;
  int t = threadIdx.x;
  int gr = crow0 + row;
  int vlim = causal ? gr + 1 : S_;
  int wlim = causal ? (((gr >> 7) + 1) << 7) : S_;
  if (wlim > S_) wlim = S_;
  float x[8];
  if (t * 8 < vlim) {
    union { ushort_t u[8]; uint4 v; } in;
    in.v = *(const uint4*)(rp + t * 8);
#pragma unroll
    for (int j = 0; j < 8; ++j) x[j] = bf2f(in.u[j]);
  } else {
#pragma unroll
    for (int j = 0; j < 8; ++j) x[j] = -3.0e38f;
  }
  float m = -3.0e38f;
#pragma unroll
  for (int j = 0; j < 8; ++j) if (t * 8 + j < vlim) m = fmaxf(m, x[j]);
  for (int mk = 1; mk < 64; mk <<= 1) m = fmaxf(m, __shfl_xor(m, mk));
  __shared__ float rbuf[8];
  if ((t & 63) == 0) rbuf[t >> 6] = m;
  __syncthreads();
  m = fmaxf(fmaxf(rbuf[0], rbuf[1]), fmaxf(rbuf[2], rbuf[3]));
  float p[8]; float l = 0.f;
#pragma unroll
  for (int j = 0; j < 8; ++j) { p[j] = (t * 8 + j < vlim) ? __expf(x[j] - m) : 0.f; l += p[j]; }
  for (int mk = 1; mk < 64; mk <<= 1) l += __shfl_xor(l, mk);
  if ((t & 63) == 0) rbuf[4 + (t >> 6)] = l;
  __syncthreads();
  l = rbuf[4] + rbuf[5] + rbuf[6] + rbuf[7];
  float inv = 1.f / l;
  if (t * 8 < wlim) {
    union { ushort_t u[8]; uint4 v; } pk;
#pragma unroll
    for (int j = 0; j < 8; ++j) pk.u[j] = f2bf(p[j] * inv);
    *(uint4*)(rp + t * 8) = pk.v;
  }
}

// ---------------------------------------------------------------------------
// out = LN(base + delta) * g + be; writes fp32 (residual) and optional bf16.
// ---------------------------------------------------------------------------
__global__ __launch_bounds__(256) void add_ln_k(
    const float* __restrict__ base, const float* __restrict__ delta,
    const float* __restrict__ g, const float* __restrict__ be,
    float* __restrict__ outf, ushort_t* __restrict__ outb) {
  int row = blockIdx.x * 4 + (threadIdx.x >> 6);
  int lane = threadIdx.x & 63;
  size_t off = (size_t)row * 256 + lane * 4;
  float4 xv = *(const float4*)(base + off);
  float4 dv = *(const float4*)(delta + off);
  float s0 = xv.x + dv.x, s1 = xv.y + dv.y, s2 = xv.z + dv.z, s3 = xv.w + dv.w;
  float sum = s0 + s1 + s2 + s3;
  for (int mk = 1; mk < 64; mk <<= 1) sum += __shfl_xor(sum, mk);
  float mean = sum * (1.f / 256.f);
  float e0 = s0 - mean, e1 = s1 - mean, e2 = s2 - mean, e3 = s3 - mean;
  float ss = e0 * e0 + e1 * e1 + e2 * e2 + e3 * e3;
  for (int mk = 1; mk < 64; mk <<= 1) ss += __shfl_xor(ss, mk);
  float rstd = rsqrtf(ss * (1.f / 256.f) + 1e-5f);
  float4 gv = *(const float4*)(g + lane * 4);
  float4 bv = *(const float4*)(be + lane * 4);
  float o0 = e0 * rstd * gv.x + bv.x, o1 = e1 * rstd * gv.y + bv.y;
  float o2 = e2 * rstd * gv.z + bv.z, o3 = e3 * rstd * gv.w + bv.w;
  float4 ov; ov.x = o0; ov.y = o1; ov.z = o2; ov.w = o3;
  *(float4*)(outf + off) = ov;
  if (outb) {
    union { ushort_t u[4]; uint2 v; } pk;
    pk.u[0] = f2bf(o0); pk.u[1] = f2bf(o1); pk.u[2] = f2bf(o2); pk.u[3] = f2bf(o3);
    *(uint2*)(outb + off) = pk.v;
  }
}

// ---------------------------------------------------------------------------
extern "C" void kernel_launch(void* const* d_in, const int* in_sizes, int n_in,
                              void* d_out, int out_size, void* d_ws, size_t ws_size,
                              hipStream_t stream) {
  const float* y   = (const float*)d_in[0];
  const float* Z   = (const float*)d_in[1];
  const float* Wq1 = (const float*)d_in[3];  const float* bq1 = (const float*)d_in[4];
  const float* Wk1 = (const float*)d_in[5];  const float* bk1 = (const float*)d_in[6];
  const float* Wv1 = (const float*)d_in[7];  const float* bv1 = (const float*)d_in[8];
  const float* Wq2 = (const float*)d_in[9];  const float* bq2 = (const float*)d_in[10];
  const float* Wk2 = (const float*)d_in[11]; const float* bk2 = (const float*)d_in[12];
  const float* Wv2 = (const float*)d_in[13]; const float* bv2 = (const float*)d_in[14];
  const float* W1  = (const float*)d_in[15]; const float* b1  = (const float*)d_in[16];
  const float* W2  = (const float*)d_in[17]; const float* b2  = (const float*)d_in[18];
  const float* g1  = (const float*)d_in[19]; const float* be1 = (const float*)d_in[20];
  const float* g2  = (const float*)d_in[21]; const float* be2 = (const float*)d_in[22];
  const float* g3  = (const float*)d_in[23]; const float* be3 = (const float*)d_in[24];
  float* out = (float*)d_out;

  char* p = (char*)d_ws;
  auto alloc = [&](size_t sz) { char* r = p; p += (sz + 255) & ~(size_t)255; return r; };
  const size_t NBT = (size_t)B_ * T_ * D_;   // 2,097,152 elems
  ushort_t* Wq1t = (ushort_t*)alloc(D_ * D_ * 2);
  ushort_t* Wk1t = (ushort_t*)alloc(D_ * D_ * 2);
  ushort_t* Wv1t = (ushort_t*)alloc(D_ * D_ * 2);
  ushort_t* Wq2t = (ushort_t*)alloc(D_ * D_ * 2);
  ushort_t* Wk2t = (ushort_t*)alloc(D_ * D_ * 2);
  ushort_t* Wv2t = (ushort_t*)alloc(D_ * D_ * 2);
  ushort_t* W1t  = (ushort_t*)alloc((size_t)F_ * D_ * 2);
  ushort_t* W2t  = (ushort_t*)alloc((size_t)D_ * F_ * 2);
  float* bqkv1 = (float*)alloc(768 * 4);
  float* bkv2  = (float*)alloc(512 * 4);
  ushort_t* yb  = (ushort_t*)alloc(NBT * 2);
  ushort_t* Zb  = (ushort_t*)alloc(NBT * 2);
  float*    y1f = (float*)alloc(NBT * 4);
  ushort_t* y1b = (ushort_t*)alloc(NBT * 2);
  float*    y2f = (float*)alloc(NBT * 4);
  ushort_t* y2b = (ushort_t*)alloc(NBT * 2);
  ushort_t* QKVb = (ushort_t*)alloc((size_t)B_ * T_ * 768 * 2);  // [8192,768]
  ushort_t* Vt   = (ushort_t*)alloc(NBT * 2);                    // [B][D][S]
  ushort_t* Hb = QKVb;   // FFN hidden [8192,1024] aliases QKVb+Vt
  float* tmp = (float*)alloc(NBT * 4);
  ushort_t* sc = (ushort_t*)p;                                   // bf16 scores
  size_t remain = (ws_size > (size_t)(p - (char*)d_ws))
                      ? ws_size - (size_t)(p - (char*)d_ws) : 0;
  const size_t rowb = (size_t)S_ * 2;
  int CH = 0, TC = 0;
  if (remain >= (size_t)B_ * T_ * rowb)      { CH = B_; TC = T_; }
  else if (remain >= (size_t)T_ * rowb)      { CH = 1;  TC = T_; }
  else {
    int tc = (int)(remain / (rowb * 128)) * 128;
    if (tc > T_) tc = T_;
    CH = 1; TC = tc;
  }

  // --- prep ---
  WP8 wp;
  wp.m[0] = {Wq1, Wq1t, D_, D_}; wp.m[1] = {Wk1, Wk1t, D_, D_};
  wp.m[2] = {Wv1, Wv1t, D_, D_}; wp.m[3] = {Wq2, Wq2t, D_, D_};
  wp.m[4] = {Wk2, Wk2t, D_, D_}; wp.m[5] = {Wv2, Wv2t, D_, D_};
  wp.m[6] = {W1, W1t, D_, F_};   wp.m[7] = {W2, W2t, F_, D_};
  prep_weights_k<<<dim3(16, 16, 8), dim3(64, 4), 0, stream>>>(wp);
  pack_bias_k<<<dim3(5), 256, 0, stream>>>(bq1, bk1, bv1, bk2, bv2, bqkv1, bkv2);
  cvt_k<<<dim3((int)(NBT / 8 / 256), 2), 256, 0, stream>>>(y, yb, Zb ? Z : Z, Zb);

  // big=true -> 128x128 tile (use when N % 128 == 0 and grid stays >= ~256)
  auto gemm = [&](const ushort_t* A, int lda, long long sAz,
                  const ushort_t* Bt, int ldb, long long sBz,
                  const float* bias, float* Cf, ushort_t* Cb, int ldc, long long sCz,
                  int M, int N, int K, float alpha, int causal, int kcausal,
                  bool relu, int Zn, int crow0, bool big) {
    if (big) {
      dim3 g(N / 128, M / 128, Zn);
      if (relu)
        gemm_bt128<true><<<g, 256, 0, stream>>>(A, lda, sAz, Bt, ldb, sBz, bias, Cf, Cb, ldc, sCz, K, alpha, causal, crow0);
      else
        gemm_bt128<false><<<g, 256, 0, stream>>>(A, lda, sAz, Bt, ldb, sBz, bias, Cf, Cb, ldc, sCz, K, alpha, causal, crow0);
    } else {
      dim3 g(N / 64, M / 128, Zn);
      if (relu)
        gemm_bt<true><<<g, 256, 0, stream>>>(A, lda, sAz, Bt, ldb, sBz, bias, Cf, Cb, ldc, sCz, K, alpha, causal, kcausal, crow0);
      else
        gemm_bt<false><<<g, 256, 0, stream>>>(A, lda, sAz, Bt, ldb, sBz, bias, Cf, Cb, ldc, sCz, K, alpha, causal, kcausal, crow0);
    }
  };

  // attention over interleaved QKV buffer: Q at col 0, K at col 256, V at col 512
  auto attention = [&](float* attout, int causal) {
    transpose_bf16_k<<<dim3(S_ / 64, D_ / 64, B_), dim3(64, 4), 0, stream>>>(
        QKVb + 512, (long long)S_ * 768, 768, Vt, (long long)D_ * S_, S_, D_);
    if (TC <= 0) return;
    const ushort_t* Q = QKVb;
    const ushort_t* Kc = QKVb + 256;
    for (int b0 = 0; b0 < B_; b0 += CH) {
      for (int t0 = 0; t0 < T_; t0 += TC) {
        int rows = (t0 + TC <= T_) ? TC : (T_ - t0);
        // QK^T (128x128 tile, N=2048)
        gemm(Q + ((size_t)b0 * T_ + t0) * 768, 768, (long long)T_ * 768,
             Kc + (size_t)b0 * S_ * 768, 768, (long long)S_ * 768,
             nullptr, nullptr, sc, S_, (long long)T_ * S_,
             rows, S_, D_, 0.0625f, causal, 0, false, CH, t0, true);
        softmax_k<<<dim3(rows, CH), 256, 0, stream>>>(sc, causal, t0);
        // PV (128x64 tile, N=256; kcausal trims K loop)
        gemm(sc, S_, (long long)T_ * S_,
             Vt + (size_t)b0 * D_ * S_, S_, (long long)D_ * S_,
             nullptr, attout + ((size_t)b0 * T_ + t0) * D_, nullptr, D_, (long long)T_ * D_,
             rows, D_, S_, 1.f, 0, causal, false, CH, t0, false);
      }
    }
  };

  // --- self-attention ---
  gemm(yb, D_, 0, Wq1t, D_, 0, bqkv1, nullptr, QKVb, 768, 0,
       B_ * T_, 768, D_, 1.f, 0, 0, false, 1, 0, true);
  attention(tmp, 1);
  add_ln_k<<<dim3(B_ * T_ / 4), 256, 0, stream>>>(y, tmp, g1, be1, y1f, y1b);

  // --- cross-attention ---
  gemm(y1b, D_, 0, Wq2t, D_, 0, bq2, nullptr, QKVb, 768, 0,
       B_ * T_, D_, D_, 1.f, 0, 0, false, 1, 0, false);
  gemm(Zb, D_, 0, Wk2t, D_, 0, bkv2, nullptr, QKVb + 256, 768, 0,
       B_ * S_, 512, D_, 1.f, 0, 0, false, 1, 0, true);
  attention(tmp, 0);
  add_ln_k<<<dim3(B_ * T_ / 4), 256, 0, stream>>>(y1f, tmp, g2, be2, y2f, y2b);

  // --- FFN ---
  gemm(y2b, D_, 0, W1t, D_, 0, b1, nullptr, Hb, F_, 0,
       B_ * T_, F_, D_, 1.f, 0, 0, true, 1, 0, true);
  gemm(Hb, F_, 0, W2t, F_, 0, b2, tmp, nullptr, D_, 0,
       B_ * T_, D_, F_, 1.f, 0, 0, false, 1, 0, false);
  add_ln_k<<<dim3(B_ * T_ / 4), 256, 0, stream>>>(y2f, tmp, g3, be3, out, nullptr);
}

// Round 10
// 312.206 us; speedup vs baseline: 1.8443x; 1.0995x over previous
//
#include <hip/hip_runtime.h>

#define B_ 4
#define T_ 2048
#define S_ 2048
#define D_ 256
#define F_ 1024

typedef unsigned short ushort_t;
typedef __bf16 v8bf __attribute__((ext_vector_type(8)));
typedef float v4f __attribute__((ext_vector_type(4)));
typedef __attribute__((address_space(1))) const unsigned int gas_uint;
typedef __attribute__((address_space(3))) unsigned int las_uint;

__device__ __forceinline__ ushort_t f2bf(float f) {
  unsigned u = __float_as_uint(f);
  unsigned r = (u + 0x7FFFu + ((u >> 16) & 1u)) >> 16;   // RTNE
  return (ushort_t)r;
}
__device__ __forceinline__ float bf2f(ushort_t u) {
  return __uint_as_float((unsigned)u << 16);
}

// ---------------------------------------------------------------------------
// prep_all: z<8 -> weight fp32 [K,N] -> bf16 [N,K] tiles; z>=8 -> y/Z cvt.
// grid (16,16,16), block (64,4).
// ---------------------------------------------------------------------------
struct WP { const float* s; ushort_t* d; int K, N; };
struct WP8 { WP m[8]; };

__global__ void prep_all_k(WP8 a, const float* __restrict__ y, ushort_t* __restrict__ yb,
                           const float* __restrict__ Z, ushort_t* __restrict__ Zb) {
  if (blockIdx.z < 8) {
    WP w = a.m[blockIdx.z];
    int k0 = blockIdx.x * 64, n0 = blockIdx.y * 64;
    if (k0 >= w.K || n0 >= w.N) return;
    __shared__ ushort_t tile[64][65];
    int tx = threadIdx.x, ty = threadIdx.y;
    for (int r = ty; r < 64; r += 4)
      tile[r][tx] = f2bf(w.s[(size_t)(k0 + r) * w.N + n0 + tx]);
    __syncthreads();
    for (int r = ty; r < 64; r += 4)
      w.d[(size_t)(n0 + r) * w.K + k0 + tx] = tile[tx][r];
  } else {
    int s = blockIdx.z - 8;                       // 0..7
    const float* src = (s >= 4) ? Z : y;
    ushort_t* dst = (s >= 4) ? Zb : yb;
    int lid = (s & 3) * 256 + blockIdx.y * 16 + blockIdx.x;   // 0..1023
    int tid = threadIdx.y * 64 + threadIdx.x;
    size_t off = (size_t)lid * 2048 + (size_t)tid * 8;
    float4 v0 = *(const float4*)(src + off);
    float4 v1 = *(const float4*)(src + off + 4);
    union { ushort_t u[8]; uint4 v; } pk;
    pk.u[0] = f2bf(v0.x); pk.u[1] = f2bf(v0.y); pk.u[2] = f2bf(v0.z); pk.u[3] = f2bf(v0.w);
    pk.u[4] = f2bf(v1.x); pk.u[5] = f2bf(v1.y); pk.u[6] = f2bf(v1.z); pk.u[7] = f2bf(v1.w);
    *(uint4*)(dst + off) = pk.v;
  }
}

// ---------------------------------------------------------------------------
// Merged V transposes: z<4 -> V1 (QKVb+512, ld 768) -> Vt1;  z>=4 -> V2
// (QKV2b+256, ld 512) -> Vt2.
// ---------------------------------------------------------------------------
__global__ void transpose_v_k(const ushort_t* __restrict__ V1, ushort_t* __restrict__ Vt1,
                              const ushort_t* __restrict__ V2, ushort_t* __restrict__ Vt2) {
  int z = blockIdx.z;
  const ushort_t* in;
  ushort_t* out;
  int ldin;
  if (z < 4) { in = V1 + (size_t)z * T_ * 768; out = Vt1 + (size_t)z * D_ * S_; ldin = 768; }
  else       { in = V2 + (size_t)(z - 4) * S_ * 512; out = Vt2 + (size_t)(z - 4) * D_ * S_; ldin = 512; }
  __shared__ ushort_t tile[64][65];
  int r0 = blockIdx.x * 64, c0 = blockIdx.y * 64;
  int tx = threadIdx.x, ty = threadIdx.y;
  for (int r = ty; r < 64; r += 4)
    tile[r][tx] = in[(size_t)(r0 + r) * ldin + c0 + tx];
  __syncthreads();
  for (int r = ty; r < 64; r += 4)
    out[(size_t)(c0 + r) * S_ + r0 + tx] = tile[tx][r];
}

// ---------------------------------------------------------------------------
// GEMM 128x64 tile (verified r2): C = alpha*A@Bt^T + bias.
// ---------------------------------------------------------------------------
template<bool RELU>
__global__ __launch_bounds__(256, 2) void gemm_bt(
    const ushort_t* __restrict__ A, int lda, long long sAz,
    const ushort_t* __restrict__ Bt, int ldb, long long sBz,
    const float* __restrict__ bias,
    float* __restrict__ Cf, ushort_t* __restrict__ Cb, int ldc, long long sCz,
    int K, float alpha, int causal, int kcausal, int crow0) {
  const int n0 = blockIdx.x * 64, m0 = blockIdx.y * 128;
  if (causal && n0 > crow0 + m0 + 127) return;
  const int Keff = kcausal ? ((crow0 + m0 + 128 < K) ? crow0 + m0 + 128 : K) : K;
  A  += (long long)blockIdx.z * sAz;
  Bt += (long long)blockIdx.z * sBz;
  const long long coff = (long long)blockIdx.z * sCz;
  const int t = threadIdx.x, lane = t & 63, wv = t >> 6;
  const int wm = wv >> 1, wn = wv & 1;
  const int kslot = lane >> 4, l15 = lane & 15;
  __shared__ __align__(16) char smem[24576];
  char* sA = smem;
  char* sB = smem + 16384;

  v4f acc[4][2];
  v4f zero = {0.f, 0.f, 0.f, 0.f};
#pragma unroll
  for (int m = 0; m < 4; ++m)
#pragma unroll
    for (int n = 0; n < 2; ++n) acc[m][n] = zero;

  for (int kk = 0; kk < Keff; kk += 64) {
    __syncthreads();
#pragma unroll
    for (int q = 0; q < 4; ++q) {
      int g = q * 256 + t;
      int row = g >> 3, j = g & 7;
      const ushort_t* src = A + (long long)(m0 + row) * lda + kk + ((j ^ (row & 7)) << 3);
      __builtin_amdgcn_global_load_lds((gas_uint*)src,
          (las_uint*)(sA + q * 4096 + (wv << 10)), 16, 0, 0);
    }
#pragma unroll
    for (int q = 0; q < 2; ++q) {
      int g = q * 256 + t;
      int row = g >> 3, j = g & 7;
      const ushort_t* src = Bt + (long long)(n0 + row) * ldb + kk + ((j ^ (row & 7)) << 3);
      __builtin_amdgcn_global_load_lds((gas_uint*)src,
          (las_uint*)(sB + q * 4096 + (wv << 10)), 16, 0, 0);
    }
    __syncthreads();
#pragma unroll
    for (int ks = 0; ks < 2; ++ks) {
      v8bf af[4]; v8bf bfr[2];
#pragma unroll
      for (int m = 0; m < 4; ++m) {
        int row = wm * 64 + m * 16 + l15;
        int gs = (ks * 4 + kslot) ^ (row & 7);
        af[m] = *(const v8bf*)(sA + ((row * 8 + gs) << 4));
      }
#pragma unroll
      for (int n = 0; n < 2; ++n) {
        int row = wn * 32 + n * 16 + l15;
        int gs = (ks * 4 + kslot) ^ (row & 7);
        bfr[n] = *(const v8bf*)(sB + ((row * 8 + gs) << 4));
      }
#pragma unroll
      for (int m = 0; m < 4; ++m)
#pragma unroll
        for (int n = 0; n < 2; ++n)
          acc[m][n] = __builtin_amdgcn_mfma_f32_16x16x32_bf16(af[m], bfr[n], acc[m][n], 0, 0, 0);
    }
  }
#pragma unroll
  for (int m = 0; m < 4; ++m) {
    int grow0 = m0 + wm * 64 + m * 16 + (kslot << 2);
#pragma unroll
    for (int n = 0; n < 2; ++n) {
      int gcol = n0 + wn * 32 + n * 16 + l15;
      float bb = bias ? bias[gcol] : 0.f;
#pragma unroll
      for (int i = 0; i < 4; ++i) {
        float v = acc[m][n][i] * alpha + bb;
        if (RELU) v = fmaxf(v, 0.f);
        long long off = coff + (long long)(grow0 + i) * ldc + gcol;
        if (Cf) Cf[off] = v;
        if (Cb) Cb[off] = f2bf(v);
      }
    }
  }
}

// ---------------------------------------------------------------------------
// GEMM 128x128 tile (verified r7).
// ---------------------------------------------------------------------------
template<bool RELU>
__global__ __launch_bounds__(256, 2) void gemm_bt128(
    const ushort_t* __restrict__ A, int lda, long long sAz,
    const ushort_t* __restrict__ Bt, int ldb, long long sBz,
    const float* __restrict__ bias,
    float* __restrict__ Cf, ushort_t* __restrict__ Cb, int ldc, long long sCz,
    int K, float alpha, int causal, int crow0) {
  const int n0 = blockIdx.x * 128, m0 = blockIdx.y * 128;
  if (causal && n0 > crow0 + m0 + 127) return;
  A  += (long long)blockIdx.z * sAz;
  Bt += (long long)blockIdx.z * sBz;
  const long long coff = (long long)blockIdx.z * sCz;
  const int t = threadIdx.x, lane = t & 63, wv = t >> 6;
  const int wm = wv >> 1, wn = wv & 1;
  const int kslot = lane >> 4, l15 = lane & 15;
  __shared__ __align__(16) char smem[32768];
  char* sA = smem;
  char* sB = smem + 16384;

  v4f acc[4][4];
  v4f zero = {0.f, 0.f, 0.f, 0.f};
#pragma unroll
  for (int m = 0; m < 4; ++m)
#pragma unroll
    for (int n = 0; n < 4; ++n) acc[m][n] = zero;

  for (int kk = 0; kk < K; kk += 64) {
    __syncthreads();
#pragma unroll
    for (int q = 0; q < 4; ++q) {
      int g = q * 256 + t;
      int row = g >> 3, j = g & 7;
      const ushort_t* src = A + (long long)(m0 + row) * lda + kk + ((j ^ (row & 7)) << 3);
      __builtin_amdgcn_global_load_lds((gas_uint*)src,
          (las_uint*)(sA + q * 4096 + (wv << 10)), 16, 0, 0);
    }
#pragma unroll
    for (int q = 0; q < 4; ++q) {
      int g = q * 256 + t;
      int row = g >> 3, j = g & 7;
      const ushort_t* src = Bt + (long long)(n0 + row) * ldb + kk + ((j ^ (row & 7)) << 3);
      __builtin_amdgcn_global_load_lds((gas_uint*)src,
          (las_uint*)(sB + q * 4096 + (wv << 10)), 16, 0, 0);
    }
    __syncthreads();
#pragma unroll
    for (int ks = 0; ks < 2; ++ks) {
      v8bf af[4]; v8bf bfr[4];
#pragma unroll
      for (int m = 0; m < 4; ++m) {
        int row = wm * 64 + m * 16 + l15;
        int gs = (ks * 4 + kslot) ^ (row & 7);
        af[m] = *(const v8bf*)(sA + ((row * 8 + gs) << 4));
      }
#pragma unroll
      for (int n = 0; n < 4; ++n) {
        int row = wn * 64 + n * 16 + l15;
        int gs = (ks * 4 + kslot) ^ (row & 7);
        bfr[n] = *(const v8bf*)(sB + ((row * 8 + gs) << 4));
      }
#pragma unroll
      for (int m = 0; m < 4; ++m)
#pragma unroll
        for (int n = 0; n < 4; ++n)
          acc[m][n] = __builtin_amdgcn_mfma_f32_16x16x32_bf16(af[m], bfr[n], acc[m][n], 0, 0, 0);
    }
  }
#pragma unroll
  for (int m = 0; m < 4; ++m) {
    int grow0 = m0 + wm * 64 + m * 16 + (kslot << 2);
#pragma unroll
    for (int n = 0; n < 4; ++n) {
      int gcol = n0 + wn * 64 + n * 16 + l15;
      float bb = bias ? bias[gcol] : 0.f;
#pragma unroll
      for (int i = 0; i < 4; ++i) {
        float v = acc[m][n][i] * alpha + bb;
        if (RELU) v = fmaxf(v, 0.f);
        long long off = coff + (long long)(grow0 + i) * ldc + gcol;
        if (Cf) Cf[off] = v;
        if (Cb) Cb[off] = f2bf(v);
      }
    }
  }
}

// ---------------------------------------------------------------------------
// Merged projection GEMM (gemm_bt128 body): z=0: yb@Wqkv1 -> QKVb[8192,768];
// z=1: Zb@Wkv2 -> QKV2b[8192,512].  Inline bias select replaces pack_bias.
// ---------------------------------------------------------------------------
__global__ __launch_bounds__(256, 2) void gemm_proj(
    const ushort_t* __restrict__ yb, const ushort_t* __restrict__ Zb,
    const ushort_t* __restrict__ Wqkv1t, const ushort_t* __restrict__ Wkv2t,
    ushort_t* __restrict__ QKVb, ushort_t* __restrict__ QKV2b,
    const float* bq1, const float* bk1, const float* bv1,
    const float* bk2, const float* bv2) {
  const int z = blockIdx.z;
  const int n0 = blockIdx.x * 128, m0 = blockIdx.y * 128;
  if (z == 1 && n0 >= 512) return;
  const ushort_t* A  = z ? Zb : yb;        const int lda = 256;
  const ushort_t* Bt = z ? Wkv2t : Wqkv1t; const int ldb = 256;
  ushort_t* Cb = z ? QKV2b : QKVb;         const int ldc = z ? 512 : 768;
  const int t = threadIdx.x, lane = t & 63, wv = t >> 6;
  const int wm = wv >> 1, wn = wv & 1;
  const int kslot = lane >> 4, l15 = lane & 15;
  __shared__ __align__(16) char smem[32768];
  char* sA = smem;
  char* sB = smem + 16384;

  v4f acc[4][4];
  v4f zero = {0.f, 0.f, 0.f, 0.f};
#pragma unroll
  for (int m = 0; m < 4; ++m)
#pragma unroll
    for (int n = 0; n < 4; ++n) acc[m][n] = zero;

  for (int kk = 0; kk < 256; kk += 64) {
    __syncthreads();
#pragma unroll
    for (int q = 0; q < 4; ++q) {
      int g = q * 256 + t;
      int row = g >> 3, j = g & 7;
      const ushort_t* src = A + (long long)(m0 + row) * lda + kk + ((j ^ (row & 7)) << 3);
      __builtin_amdgcn_global_load_lds((gas_uint*)src,
          (las_uint*)(sA + q * 4096 + (wv << 10)), 16, 0, 0);
    }
#pragma unroll
    for (int q = 0; q < 4; ++q) {
      int g = q * 256 + t;
      int row = g >> 3, j = g & 7;
      const ushort_t* src = Bt + (long long)(n0 + row) * ldb + kk + ((j ^ (row & 7)) << 3);
      __builtin_amdgcn_global_load_lds((gas_uint*)src,
          (las_uint*)(sB + q * 4096 + (wv << 10)), 16, 0, 0);
    }
    __syncthreads();
#pragma unroll
    for (int ks = 0; ks < 2; ++ks) {
      v8bf af[4]; v8bf bfr[4];
#pragma unroll
      for (int m = 0; m < 4; ++m) {
        int row = wm * 64 + m * 16 + l15;
        int gs = (ks * 4 + kslot) ^ (row & 7);
        af[m] = *(const v8bf*)(sA + ((row * 8 + gs) << 4));
      }
#pragma unroll
      for (int n = 0; n < 4; ++n) {
        int row = wn * 64 + n * 16 + l15;
        int gs = (ks * 4 + kslot) ^ (row & 7);
        bfr[n] = *(const v8bf*)(sB + ((row * 8 + gs) << 4));
      }
#pragma unroll
      for (int m = 0; m < 4; ++m)
#pragma unroll
        for (int n = 0; n < 4; ++n)
          acc[m][n] = __builtin_amdgcn_mfma_f32_16x16x32_bf16(af[m], bfr[n], acc[m][n], 0, 0, 0);
    }
  }
#pragma unroll
  for (int m = 0; m < 4; ++m) {
    int grow0 = m0 + wm * 64 + m * 16 + (kslot << 2);
#pragma unroll
    for (int n = 0; n < 4; ++n) {
      int gcol = n0 + wn * 64 + n * 16 + l15;
      float bb;
      if (z == 0)
        bb = (gcol < 256) ? bq1[gcol] : (gcol < 512) ? bk1[gcol - 256] : bv1[gcol - 512];
      else
        bb = (gcol < 256) ? bk2[gcol] : bv2[gcol - 256];
#pragma unroll
      for (int i = 0; i < 4; ++i)
        Cb[(long long)(grow0 + i) * ldc + gcol] = f2bf(acc[m][n][i] + bb);
    }
  }
}

// ---------------------------------------------------------------------------
// Row softmax (verified r7): bf16 in place, causal-trimmed.
// ---------------------------------------------------------------------------
__global__ __launch_bounds__(256) void softmax_k(ushort_t* sc, int causal, int crow0) {
  int row = blockIdx.x;
  ushort_t* rp = sc + ((size_t)blockIdx.y * T_ + row) * S_;
  int t = threadIdx.x;
  int gr = crow0 + row;
  int vlim = causal ? gr + 1 : S_;
  int wlim = causal ? (((gr >> 7) + 1) << 7) : S_;
  if (wlim > S_) wlim = S_;
  float x[8];
  if (t * 8 < vlim) {
    union { ushort_t u[8]; uint4 v; } in;
    in.v = *(const uint4*)(rp + t * 8);
#pragma unroll
    for (int j = 0; j < 8; ++j) x[j] = bf2f(in.u[j]);
  } else {
#pragma unroll
    for (int j = 0; j < 8; ++j) x[j] = -3.0e38f;
  }
  float m = -3.0e38f;
#pragma unroll
  for (int j = 0; j < 8; ++j) if (t * 8 + j < vlim) m = fmaxf(m, x[j]);
  for (int mk = 1; mk < 64; mk <<= 1) m = fmaxf(m, __shfl_xor(m, mk));
  __shared__ float rbuf[8];
  if ((t & 63) == 0) rbuf[t >> 6] = m;
  __syncthreads();
  m = fmaxf(fmaxf(rbuf[0], rbuf[1]), fmaxf(rbuf[2], rbuf[3]));
  float p[8]; float l = 0.f;
#pragma unroll
  for (int j = 0; j < 8; ++j) { p[j] = (t * 8 + j < vlim) ? __expf(x[j] - m) : 0.f; l += p[j]; }
  for (int mk = 1; mk < 64; mk <<= 1) l += __shfl_xor(l, mk);
  if ((t & 63) == 0) rbuf[4 + (t >> 6)] = l;
  __syncthreads();
  l = rbuf[4] + rbuf[5] + rbuf[6] + rbuf[7];
  float inv = 1.f / l;
  if (t * 8 < wlim) {
    union { ushort_t u[8]; uint4 v; } pk;
#pragma unroll
    for (int j = 0; j < 8; ++j) pk.u[j] = f2bf(p[j] * inv);
    *(uint4*)(rp + t * 8) = pk.v;
  }
}

// ---------------------------------------------------------------------------
// Fused [A@Bt^T + bias + base] -> LayerNorm -> outf (fp32) / outb (bf16).
// Tile: 32 rows x 256 cols, 4 waves along N (each 32x64, acc 2x4).
// KCAUSAL trims K to round64(crow0+m0+32) for causal PV.
// ---------------------------------------------------------------------------
template<int KCAUSAL>
__global__ __launch_bounds__(256, 2) void pv_ln_k(
    const ushort_t* __restrict__ A, int lda, long long sAz,
    const ushort_t* __restrict__ Bt, int ldb, long long sBz,
    const float* __restrict__ bias,
    const float* __restrict__ base, long long sBasez,
    const float* __restrict__ g, const float* __restrict__ be,
    float* __restrict__ outf, ushort_t* __restrict__ outb, long long sOz,
    int K, int crow0) {
  const int m0 = blockIdx.x * 32;
  A  += (long long)blockIdx.z * sAz;
  Bt += (long long)blockIdx.z * sBz;
  const long long boff = (long long)blockIdx.z * sBasez;
  const long long ooff = (long long)blockIdx.z * sOz;
  const int t = threadIdx.x, lane = t & 63, wn = t >> 6;
  const int kslot = lane >> 4, l15 = lane & 15;
  __shared__ __align__(16) char sA[4096];    // [32][64] bf16
  __shared__ __align__(16) char sB[32768];   // [256][64] bf16
  __shared__ float sSum[32][4], sSq[32][4];

  int Keff = K;
  if (KCAUSAL) {
    int kb = ((crow0 + m0 + 32 + 63) >> 6) << 6;
    Keff = (kb < K) ? kb : K;
  }

  v4f acc[2][4];
  v4f zero = {0.f, 0.f, 0.f, 0.f};
#pragma unroll
  for (int m = 0; m < 2; ++m)
#pragma unroll
    for (int n = 0; n < 4; ++n) acc[m][n] = zero;

  for (int kk = 0; kk < Keff; kk += 64) {
    __syncthreads();
    {   // A tile: 256 granules, 1 per thread
      int row = t >> 3, j = t & 7;
      const ushort_t* src = A + (long long)(m0 + row) * lda + kk + ((j ^ (row & 7)) << 3);
      __builtin_amdgcn_global_load_lds((gas_uint*)src,
          (las_uint*)(sA + (wn << 10)), 16, 0, 0);
    }
#pragma unroll
    for (int q = 0; q < 8; ++q) {   // B tile: 2048 granules, 8 per thread
      int gidx = q * 256 + t;
      int row = gidx >> 3, j = gidx & 7;
      const ushort_t* src = Bt + (long long)row * ldb + kk + ((j ^ (row & 7)) << 3);
      __builtin_amdgcn_global_load_lds((gas_uint*)src,
          (las_uint*)(sB + q * 4096 + (wn << 10)), 16, 0, 0);
    }
    __syncthreads();
#pragma unroll
    for (int ks = 0; ks < 2; ++ks) {
      v8bf af[2]; v8bf bfr[4];
#pragma unroll
      for (int m = 0; m < 2; ++m) {
        int row = m * 16 + l15;
        int gs = (ks * 4 + kslot) ^ (row & 7);
        af[m] = *(const v8bf*)(sA + ((row * 8 + gs) << 4));
      }
#pragma unroll
      for (int n = 0; n < 4; ++n) {
        int row = wn * 64 + n * 16 + l15;
        int gs = (ks * 4 + kslot) ^ (row & 7);
        bfr[n] = *(const v8bf*)(sB + ((row * 8 + gs) << 4));
      }
#pragma unroll
      for (int m = 0; m < 2; ++m)
#pragma unroll
        for (int n = 0; n < 4; ++n)
          acc[m][n] = __builtin_amdgcn_mfma_f32_16x16x32_bf16(af[m], bfr[n], acc[m][n], 0, 0, 0);
    }
  }

  // ---- epilogue: + bias + residual, row stats, LN, write ----
  float sum[2][4], sq[2][4];
#pragma unroll
  for (int m = 0; m < 2; ++m)
#pragma unroll
    for (int i = 0; i < 4; ++i) { sum[m][i] = 0.f; sq[m][i] = 0.f; }
#pragma unroll
  for (int m = 0; m < 2; ++m)
#pragma unroll
    for (int n = 0; n < 4; ++n) {
      int col = wn * 64 + n * 16 + l15;
      float bb = bias ? bias[col] : 0.f;
#pragma unroll
      for (int i = 0; i < 4; ++i) {
        int row = m0 + m * 16 + kslot * 4 + i;
        float v = acc[m][n][i] + bb + base[boff + (long long)row * 256 + col];
        acc[m][n][i] = v;
        sum[m][i] += v;
        sq[m][i] += v * v;
      }
    }
#pragma unroll
  for (int mk = 1; mk < 16; mk <<= 1) {
#pragma unroll
    for (int m = 0; m < 2; ++m)
#pragma unroll
      for (int i = 0; i < 4; ++i) {
        sum[m][i] += __shfl_xor(sum[m][i], mk);
        sq[m][i] += __shfl_xor(sq[m][i], mk);
      }
  }
  if (l15 == 0) {
#pragma unroll
    for (int m = 0; m < 2; ++m)
#pragma unroll
      for (int i = 0; i < 4; ++i) {
        int r = m * 16 + kslot * 4 + i;
        sSum[r][wn] = sum[m][i];
        sSq[r][wn] = sq[m][i];
      }
  }
  __syncthreads();
#pragma unroll
  for (int m = 0; m < 2; ++m)
#pragma unroll
    for (int i = 0; i < 4; ++i) {
      int r = m * 16 + kslot * 4 + i;
      float s = sSum[r][0] + sSum[r][1] + sSum[r][2] + sSum[r][3];
      float q2 = sSq[r][0] + sSq[r][1] + sSq[r][2] + sSq[r][3];
      float mean = s * (1.f / 256.f);
      float var = q2 * (1.f / 256.f) - mean * mean;
      float rstd = rsqrtf(var + 1e-5f);
      int row = m0 + r;
#pragma unroll
      for (int n = 0; n < 4; ++n) {
        int col = wn * 64 + n * 16 + l15;
        float o = (acc[m][n][i] - mean) * rstd * g[col] + be[col];
        long long off = ooff + (long long)row * 256 + col;
        outf[off] = o;
        if (outb) outb[off] = f2bf(o);
      }
    }
}

// ---------------------------------------------------------------------------
extern "C" void kernel_launch(void* const* d_in, const int* in_sizes, int n_in,
                              void* d_out, int out_size, void* d_ws, size_t ws_size,
                              hipStream_t stream) {
  const float* y   = (const float*)d_in[0];
  const float* Z   = (const float*)d_in[1];
  const float* Wq1 = (const float*)d_in[3];  const float* bq1 = (const float*)d_in[4];
  const float* Wk1 = (const float*)d_in[5];  const float* bk1 = (const float*)d_in[6];
  const float* Wv1 = (const float*)d_in[7];  const float* bv1 = (const float*)d_in[8];
  const float* Wq2 = (const float*)d_in[9];  const float* bq2 = (const float*)d_in[10];
  const float* Wk2 = (const float*)d_in[11]; const float* bk2 = (const float*)d_in[12];
  const float* Wv2 = (const float*)d_in[13]; const float* bv2 = (const float*)d_in[14];
  const float* W1  = (const float*)d_in[15]; const float* b1  = (const float*)d_in[16];
  const float* W2  = (const float*)d_in[17]; const float* b2  = (const float*)d_in[18];
  const float* g1  = (const float*)d_in[19]; const float* be1 = (const float*)d_in[20];
  const float* g2  = (const float*)d_in[21]; const float* be2 = (const float*)d_in[22];
  const float* g3  = (const float*)d_in[23]; const float* be3 = (const float*)d_in[24];
  float* out = (float*)d_out;

  char* p = (char*)d_ws;
  auto alloc = [&](size_t sz) { char* r = p; p += (sz + 255) & ~(size_t)255; return r; };
  const size_t NBT = (size_t)B_ * T_ * D_;   // 2,097,152 elems
  ushort_t* Wq1t = (ushort_t*)alloc(D_ * D_ * 2);     // Wq1t..Wv1t contiguous = Wqkv1t [768][256]
  ushort_t* Wk1t = (ushort_t*)alloc(D_ * D_ * 2);
  ushort_t* Wv1t = (ushort_t*)alloc(D_ * D_ * 2);
  ushort_t* Wq2t = (ushort_t*)alloc(D_ * D_ * 2);
  ushort_t* Wk2t = (ushort_t*)alloc(D_ * D_ * 2);     // Wk2t..Wv2t contiguous = Wkv2t [512][256]
  ushort_t* Wv2t = (ushort_t*)alloc(D_ * D_ * 2);
  ushort_t* W1t  = (ushort_t*)alloc((size_t)F_ * D_ * 2);
  ushort_t* W2t  = (ushort_t*)alloc((size_t)D_ * F_ * 2);
  ushort_t* yb  = (ushort_t*)alloc(NBT * 2);
  ushort_t* Zb  = (ushort_t*)alloc(NBT * 2);
  float*    y1f = (float*)alloc(NBT * 4);
  ushort_t* y1b = (ushort_t*)alloc(NBT * 2);
  float*    y2f = (float*)alloc(NBT * 4);
  ushort_t* y2b = (ushort_t*)alloc(NBT * 2);
  ushort_t* QKVb  = (ushort_t*)alloc((size_t)B_ * T_ * 768 * 2);  // [8192,768]
  ushort_t* QKV2b = (ushort_t*)alloc((size_t)B_ * S_ * 512 * 2);  // [8192,512]
  ushort_t* Qb  = (ushort_t*)alloc(NBT * 2);                      // cross Q [8192,256]
  ushort_t* Vt1 = (ushort_t*)alloc(NBT * 2);                      // [B][D][S]
  ushort_t* Vt2 = (ushort_t*)alloc(NBT * 2);
  ushort_t* Hb = QKVb;   // FFN hidden [8192,1024] aliases QKVb
  ushort_t* sc = (ushort_t*)p;                                    // bf16 scores
  size_t remain = (ws_size > (size_t)(p - (char*)d_ws))
                      ? ws_size - (size_t)(p - (char*)d_ws) : 0;
  const size_t rowb = (size_t)S_ * 2;
  int CH = 0, TC = 0;
  if (remain >= (size_t)B_ * T_ * rowb)      { CH = B_; TC = T_; }
  else if (remain >= (size_t)T_ * rowb)      { CH = 1;  TC = T_; }
  else {
    int tc = (int)(remain / (rowb * 128)) * 128;
    if (tc > T_) tc = T_;
    CH = 1; TC = tc;
  }

  // --- 1: prep (weights + cvt) ---
  WP8 wp;
  wp.m[0] = {Wq1, Wq1t, D_, D_}; wp.m[1] = {Wk1, Wk1t, D_, D_};
  wp.m[2] = {Wv1, Wv1t, D_, D_}; wp.m[3] = {Wq2, Wq2t, D_, D_};
  wp.m[4] = {Wk2, Wk2t, D_, D_}; wp.m[5] = {Wv2, Wv2t, D_, D_};
  wp.m[6] = {W1, W1t, D_, F_};   wp.m[7] = {W2, W2t, F_, D_};
  prep_all_k<<<dim3(16, 16, 16), dim3(64, 4), 0, stream>>>(wp, y, yb, Z, Zb);

  // --- 2: merged projections (QKV1 + KV2) ---
  gemm_proj<<<dim3(6, 64, 2), 256, 0, stream>>>(yb, Zb, Wq1t, Wk2t, QKVb, QKV2b,
                                                bq1, bk1, bv1, bk2, bv2);
  // --- 3: merged V transposes ---
  transpose_v_k<<<dim3(S_ / 64, D_ / 64, 8), dim3(64, 4), 0, stream>>>(
      QKVb + 512, Vt1, QKV2b + 256, Vt2);

  auto attention = [&](const ushort_t* Q, int ldq, long long sQz,
                       const ushort_t* Kc, int ldk, long long sKz,
                       const ushort_t* Vt, const float* basef,
                       const float* g, const float* be,
                       float* outf, ushort_t* outb, int causal) {
    if (TC <= 0) return;
    for (int b0 = 0; b0 < B_; b0 += CH) {
      for (int t0 = 0; t0 < T_; t0 += TC) {
        int rows = (t0 + TC <= T_) ? TC : (T_ - t0);
        gemm_bt128<false><<<dim3(S_ / 128, rows / 128, CH), 256, 0, stream>>>(
            Q + ((size_t)b0 * T_ + t0) * ldq, ldq, sQz,
            Kc + (size_t)b0 * S_ * ldk, ldk, sKz,
            nullptr, nullptr, sc, S_, (long long)T_ * S_,
            D_, 0.0625f, causal, t0);
        softmax_k<<<dim3(rows, CH), 256, 0, stream>>>(sc, causal, t0);
        const float* basep = basef + ((size_t)b0 * T_ + t0) * 256;
        float* outfp = outf + ((size_t)b0 * T_ + t0) * 256;
        ushort_t* outbp = outb ? outb + ((size_t)b0 * T_ + t0) * 256 : nullptr;
        if (causal)
          pv_ln_k<1><<<dim3(rows / 32, 1, CH), 256, 0, stream>>>(
              sc, S_, (long long)T_ * S_,
              Vt + (size_t)b0 * D_ * S_, S_, (long long)D_ * S_,
              nullptr, basep, (long long)T_ * 256, g, be,
              outfp, outbp, (long long)T_ * 256, S_, t0);
        else
          pv_ln_k<0><<<dim3(rows / 32, 1, CH), 256, 0, stream>>>(
              sc, S_, (long long)T_ * S_,
              Vt + (size_t)b0 * D_ * S_, S_, (long long)D_ * S_,
              nullptr, basep, (long long)T_ * 256, g, be,
              outfp, outbp, (long long)T_ * 256, S_, t0);
      }
    }
  };

  // --- self-attention (4,5,6): QK^T, softmax, PV+LN1 ---
  attention(QKVb, 768, (long long)T_ * 768, QKVb + 256, 768, (long long)S_ * 768,
            Vt1, y, g1, be1, y1f, y1b, 1);

  // --- 7: Q2 projection ---
  gemm_bt<false><<<dim3(D_ / 64, B_ * T_ / 128, 1), 256, 0, stream>>>(
      y1b, D_, 0, Wq2t, D_, 0, bq2, nullptr, Qb, D_, 0, D_, 1.f, 0, 0, 0);

  // --- cross-attention (8,9,10): QK^T, softmax, PV+LN2 ---
  attention(Qb, 256, (long long)T_ * 256, QKV2b, 512, (long long)S_ * 512,
            Vt2, y1f, g2, be2, y2f, y2b, 0);

  // --- 11: FFN1 ---
  gemm_bt128<true><<<dim3(F_ / 128, B_ * T_ / 128, 1), 256, 0, stream>>>(
      y2b, D_, 0, W1t, D_, 0, b1, nullptr, Hb, F_, 0, D_, 1.f, 0, 0);

  // --- 12: FFN2 + bias + residual + LN3 -> out ---
  pv_ln_k<0><<<dim3(B_ * T_ / 32, 1, 1), 256, 0, stream>>>(
      Hb, F_, 0, W2t, F_, 0, b2, y2f, 0, g3, be3, out, nullptr, 0, F_, 0);
}